// Round 1
// baseline (314.561 us; speedup 1.0000x reference)
//
#include <hip/hip_runtime.h>
#include <hip/hip_bf16.h>

typedef __bf16 bf16x8 __attribute__((ext_vector_type(8)));
typedef __attribute__((ext_vector_type(8))) short short8_t;
typedef __attribute__((ext_vector_type(4))) short short4_t;
typedef __attribute__((ext_vector_type(4))) float f32x4;

#define DEV __device__ __forceinline__

constexpr int Bc = 2, Sc = 2048, Ec = 1024, Hc = 16, Dc = 64;
constexpr int Mc = Bc * Sc;  // 4096

DEV short f2bf(float f) {
  unsigned int u = __builtin_bit_cast(unsigned int, f);
  unsigned int r = u + 0x7fffu + ((u >> 16) & 1u);
  return (short)(r >> 16);
}

// ---------- weight convert+transpose: w[K][N] f32 -> wt[N][K] bf16 ----------
__global__ __launch_bounds__(256) void k_wt(const float* __restrict__ w,
                                            short* __restrict__ wt) {
  __shared__ float tile[32][33];
  int bn = blockIdx.x, bk = blockIdx.y;
  int tx = threadIdx.x & 31, ty = threadIdx.x >> 5;
#pragma unroll
  for (int i = 0; i < 4; i++)
    tile[ty + i * 8][tx] = w[(size_t)(bk * 32 + ty + i * 8) * Ec + bn * 32 + tx];
  __syncthreads();
#pragma unroll
  for (int i = 0; i < 4; i++)
    wt[(size_t)(bn * 32 + ty + i * 8) * Ec + bk * 32 + tx] = f2bf(tile[tx][ty + i * 8]);
}

// ---------- GEMM: C[M,N] = A[M,K] * Bt[N,K]^T (+bias) ----------
// MODE 0: A = fp32 (converted on stage), out = bf16 [B,H,S,D] layout
// MODE 1: A = bf16, out = fp32 [M][N] with +bias +residual
template <int MODE>
__global__ __launch_bounds__(256) void k_gemm(const void* __restrict__ Ap,
                                              const short* __restrict__ Bt,
                                              const float* __restrict__ bias,
                                              const float* __restrict__ res,
                                              void* __restrict__ out) {
  __shared__ short lA[128 * 64];
  __shared__ short lB[128 * 64];
  const int t = threadIdx.x;
  const int m0 = blockIdx.y * 128, n0 = blockIdx.x * 128;
  const int lane = t & 63, wid = t >> 6;
  const int wm = wid >> 1, wn = wid & 1;

  f32x4 acc[4][4];
#pragma unroll
  for (int i = 0; i < 4; i++)
#pragma unroll
    for (int j = 0; j < 4; j++) acc[i][j] = {0.f, 0.f, 0.f, 0.f};

  for (int k0 = 0; k0 < Ec; k0 += 64) {
    // ---- stage A tile [128][64] bf16, swizzled (chunk ^= row&7)
    if constexpr (MODE == 0) {
      const float* A = (const float*)Ap;
#pragma unroll
      for (int i = 0; i < 8; i++) {
        int row = i * 16 + (t >> 4);
        int c4 = (t & 15) * 4;
        float4 v = *(const float4*)(A + (size_t)(m0 + row) * Ec + k0 + c4);
        short4_t h;
        h[0] = f2bf(v.x); h[1] = f2bf(v.y); h[2] = f2bf(v.z); h[3] = f2bf(v.w);
        int chunk = (t & 15) >> 1, jo = (t & 1) * 4;
        *(short4_t*)&lA[row * 64 + ((chunk ^ (row & 7)) << 3) + jo] = h;
      }
    } else {
      const short* A = (const short*)Ap;
#pragma unroll
      for (int i = 0; i < 4; i++) {
        int row = i * 32 + (t >> 3);
        int chunk = t & 7;
        short8_t v = *(const short8_t*)(A + (size_t)(m0 + row) * Ec + k0 + chunk * 8);
        *(short8_t*)&lA[row * 64 + ((chunk ^ (row & 7)) << 3)] = v;
      }
    }
    // ---- stage B tile [128][64] bf16 from Bt[N][K]
#pragma unroll
    for (int i = 0; i < 4; i++) {
      int row = i * 32 + (t >> 3);
      int chunk = t & 7;
      short8_t v = *(const short8_t*)(Bt + (size_t)(n0 + row) * Ec + k0 + chunk * 8);
      *(short8_t*)&lB[row * 64 + ((chunk ^ (row & 7)) << 3)] = v;
    }
    __syncthreads();
    // ---- compute
#pragma unroll
    for (int kc = 0; kc < 2; kc++) {
      bf16x8 a[4], b[4];
#pragma unroll
      for (int mf = 0; mf < 4; mf++) {
        int row = wm * 64 + mf * 16 + (lane & 15);
        int ch = (kc * 4 + (lane >> 4)) ^ (row & 7);
        a[mf] = *(const bf16x8*)&lA[row * 64 + (ch << 3)];
      }
#pragma unroll
      for (int nf = 0; nf < 4; nf++) {
        int row = wn * 64 + nf * 16 + (lane & 15);
        int ch = (kc * 4 + (lane >> 4)) ^ (row & 7);
        b[nf] = *(const bf16x8*)&lB[row * 64 + (ch << 3)];
      }
#pragma unroll
      for (int mf = 0; mf < 4; mf++)
#pragma unroll
        for (int nf = 0; nf < 4; nf++)
          acc[mf][nf] = __builtin_amdgcn_mfma_f32_16x16x32_bf16(a[mf], b[nf], acc[mf][nf], 0, 0, 0);
    }
    __syncthreads();
  }
  // ---- epilogue
#pragma unroll
  for (int mf = 0; mf < 4; mf++) {
#pragma unroll
    for (int nf = 0; nf < 4; nf++) {
      int col = n0 + wn * 64 + nf * 16 + (lane & 15);
      float bs = bias[col];
      if constexpr (MODE == 0) {
        short* o = (short*)out;
#pragma unroll
        for (int r = 0; r < 4; r++) {
          int row = m0 + wm * 64 + mf * 16 + ((lane >> 4) << 2) + r;
          float v = acc[mf][nf][r] + bs;
          // [B,H,S,D]
          size_t off = (((size_t)(row >> 11) * Hc + (col >> 6)) * Sc + (row & 2047)) * Dc + (col & 63);
          o[off] = f2bf(v);
        }
      } else {
        float* o = (float*)out;
#pragma unroll
        for (int r = 0; r < 4; r++) {
          int row = m0 + wm * 64 + mf * 16 + ((lane >> 4) << 2) + r;
          float v = acc[mf][nf][r] + bs + res[(size_t)row * Ec + col];
          o[(size_t)row * Ec + col] = v;
        }
      }
    }
  }
}

// ---------- flash attention: one block per (q-tile of 64, b*h) ----------
__global__ __launch_bounds__(256) void k_attn(const short* __restrict__ Qp,
                                              const short* __restrict__ Kp,
                                              const short* __restrict__ Vp,
                                              const int* __restrict__ maskp,
                                              short* __restrict__ ctx) {
  __shared__ short lK[64 * 64];  // [krow][d] swizzled
  __shared__ short lV[64 * 64];  // [d][krow] swizzled (V^T)
  __shared__ short lP[64 * 64];  // [qrow][krow] swizzled
  const int t = threadIdx.x, lane = t & 63, w = t >> 6;
  const int qt = blockIdx.x, bh = blockIdx.y;
  const bool causal = maskp[0] != 0;
  const int b = bh / Hc, h = bh % Hc;
  const size_t base = (size_t)bh * Sc * Dc;

  // Q fragments in registers (rows w*16 + (lane&15))
  bf16x8 aq[2];
  {
    int qr = qt * 64 + w * 16 + (lane & 15);
#pragma unroll
    for (int kc = 0; kc < 2; kc++)
      aq[kc] = *(const bf16x8*)(Qp + base + (size_t)qr * Dc + kc * 32 + ((lane >> 4) << 3));
  }
  f32x4 oacc[4];
#pragma unroll
  for (int i = 0; i < 4; i++) oacc[i] = {0.f, 0.f, 0.f, 0.f};
  float rowm[4], rowl[4];
#pragma unroll
  for (int r = 0; r < 4; r++) { rowm[r] = -INFINITY; rowl[r] = 0.f; }

  const int ktmax = causal ? qt : (Sc / 64 - 1);
  const float inv = 1.0f / (8.0f + 1e-8f);
  const int qrow_l = w * 16 + ((lane >> 4) << 2);

  for (int kt = 0; kt <= ktmax; kt++) {
    const int koff = kt * 64;
    // stage K [64][64]
#pragma unroll
    for (int i = 0; i < 2; i++) {
      int row = i * 32 + (t >> 3), chunk = t & 7;
      short8_t v = *(const short8_t*)(Kp + base + (size_t)(koff + row) * Dc + chunk * 8);
      *(short8_t*)&lK[row * 64 + ((chunk ^ (row & 7)) << 3)] = v;
    }
    // stage V^T [d][krow]
#pragma unroll
    for (int i = 0; i < 2; i++) {
      int row = i * 32 + (t >> 3), chunk = t & 7;  // row = krow
      short8_t v = *(const short8_t*)(Vp + base + (size_t)(koff + row) * Dc + chunk * 8);
#pragma unroll
      for (int j = 0; j < 8; j++) {
        int d = chunk * 8 + j;
        lV[d * 64 + (((row >> 3) ^ (d & 7)) << 3) + (row & 7)] = v[j];
      }
    }
    __syncthreads();
    // S = Q K^T  (per wave: 16 q-rows x 64 k-cols)
    f32x4 sacc[4];
#pragma unroll
    for (int nf = 0; nf < 4; nf++) sacc[nf] = {0.f, 0.f, 0.f, 0.f};
#pragma unroll
    for (int kc = 0; kc < 2; kc++) {
#pragma unroll
      for (int nf = 0; nf < 4; nf++) {
        int row = nf * 16 + (lane & 15);
        int ch = (kc * 4 + (lane >> 4)) ^ (row & 7);
        bf16x8 bk = *(const bf16x8*)&lK[row * 64 + (ch << 3)];
        sacc[nf] = __builtin_amdgcn_mfma_f32_16x16x32_bf16(aq[kc], bk, sacc[nf], 0, 0, 0);
      }
    }
    // online softmax
    float pv[4][4];
    const bool diag = causal && (kt == qt);
#pragma unroll
    for (int r = 0; r < 4; r++) {
      int qg = qt * 64 + qrow_l + r;
      float sv[4];
      float mx = -INFINITY;
#pragma unroll
      for (int nf = 0; nf < 4; nf++) {
        float s = sacc[nf][r] * inv;
        if (diag && (koff + nf * 16 + (lane & 15)) > qg) s = -INFINITY;
        sv[nf] = s;
        mx = fmaxf(mx, s);
      }
      mx = fmaxf(mx, __shfl_xor(mx, 1));
      mx = fmaxf(mx, __shfl_xor(mx, 2));
      mx = fmaxf(mx, __shfl_xor(mx, 4));
      mx = fmaxf(mx, __shfl_xor(mx, 8));
      float mn = fmaxf(rowm[r], mx);
      float corr = exp2f((rowm[r] - mn) * 1.44269504f);
      rowm[r] = mn;
      float rs = 0.f;
#pragma unroll
      for (int nf = 0; nf < 4; nf++) {
        float p = exp2f((sv[nf] - mn) * 1.44269504f);
        pv[nf][r] = p;
        rs += p;
      }
      rs += __shfl_xor(rs, 1);
      rs += __shfl_xor(rs, 2);
      rs += __shfl_xor(rs, 4);
      rs += __shfl_xor(rs, 8);
      rowl[r] = rowl[r] * corr + rs;
#pragma unroll
      for (int df = 0; df < 4; df++) oacc[df][r] *= corr;
    }
    // P -> LDS (bf16, swizzled)
#pragma unroll
    for (int nf = 0; nf < 4; nf++) {
#pragma unroll
      for (int r = 0; r < 4; r++) {
        int m = qrow_l + r;
        int col = nf * 16 + (lane & 15);
        lP[m * 64 + (((col >> 3) ^ (m & 7)) << 3) + (col & 7)] = f2bf(pv[nf][r]);
      }
    }
    __syncthreads();
    // O += P V   (A = P rows, B = V^T rows)
#pragma unroll
    for (int kc = 0; kc < 2; kc++) {
      int prow = w * 16 + (lane & 15);
      int ch = (kc * 4 + (lane >> 4)) ^ (prow & 7);
      bf16x8 ap = *(const bf16x8*)&lP[prow * 64 + (ch << 3)];
#pragma unroll
      for (int df = 0; df < 4; df++) {
        int vr = df * 16 + (lane & 15);
        int ch2 = (kc * 4 + (lane >> 4)) ^ (vr & 7);
        bf16x8 bv = *(const bf16x8*)&lV[vr * 64 + (ch2 << 3)];
        oacc[df] = __builtin_amdgcn_mfma_f32_16x16x32_bf16(ap, bv, oacc[df], 0, 0, 0);
      }
    }
    __syncthreads();
  }
  // write ctx [M][E] bf16
#pragma unroll
  for (int df = 0; df < 4; df++) {
#pragma unroll
    for (int r = 0; r < 4; r++) {
      int srow = qt * 64 + qrow_l + r;
      int col = h * 64 + df * 16 + (lane & 15);
      float v = oacc[df][r] / rowl[r];
      ctx[(size_t)(b * Sc + srow) * Ec + col] = f2bf(v);
    }
  }
}

// ---------- LayerNorm in-place on fp32 [M][E] ----------
__global__ __launch_bounds__(256) void k_ln(float* __restrict__ x,
                                            const float* __restrict__ gamma,
                                            const float* __restrict__ beta) {
  int row = blockIdx.x, t = threadIdx.x;
  float4 v = *(const float4*)(x + (size_t)row * Ec + t * 4);
  float s = v.x + v.y + v.z + v.w;
  float sq = v.x * v.x + v.y * v.y + v.z * v.z + v.w * v.w;
#pragma unroll
  for (int m = 1; m < 64; m <<= 1) {
    s += __shfl_xor(s, m);
    sq += __shfl_xor(sq, m);
  }
  __shared__ float red[8];
  if ((t & 63) == 0) {
    red[t >> 6] = s;
    red[4 + (t >> 6)] = sq;
  }
  __syncthreads();
  s = red[0] + red[1] + red[2] + red[3];
  sq = red[4] + red[5] + red[6] + red[7];
  float mu = s * (1.f / Ec);
  float var = sq * (1.f / Ec) - mu * mu;
  float rstd = rsqrtf(var + 1e-5f);
  float4 g = *(const float4*)(gamma + t * 4);
  float4 bb = *(const float4*)(beta + t * 4);
  v.x = (v.x - mu) * rstd * g.x + bb.x;
  v.y = (v.y - mu) * rstd * g.y + bb.y;
  v.z = (v.z - mu) * rstd * g.z + bb.z;
  v.w = (v.w - mu) * rstd * g.w + bb.w;
  *(float4*)(x + (size_t)row * Ec + t * 4) = v;
}

extern "C" void kernel_launch(void* const* d_in, const int* in_sizes, int n_in,
                              void* d_out, int out_size, void* d_ws, size_t ws_size,
                              hipStream_t stream) {
  const float* q = (const float*)d_in[0];
  const float* k = (const float*)d_in[1];
  const float* v = (const float*)d_in[2];
  const float* wq = (const float*)d_in[3];
  const float* bq = (const float*)d_in[4];
  const float* wk = (const float*)d_in[5];
  const float* bk = (const float*)d_in[6];
  const float* wv = (const float*)d_in[7];
  const float* bv = (const float*)d_in[8];
  const float* wo = (const float*)d_in[9];
  const float* bo = (const float*)d_in[10];
  const float* gamma = (const float*)d_in[11];
  const float* beta = (const float*)d_in[12];
  const int* maskp = (const int*)d_in[13];
  float* out = (float*)d_out;

  short* wtq = (short*)d_ws;  // [N][K] bf16, 1M elements each
  short* wtk = wtq + (size_t)Ec * Ec;
  short* wtv = wtk + (size_t)Ec * Ec;
  short* wto = wtv + (size_t)Ec * Ec;
  short* Qp = wto + (size_t)Ec * Ec;  // [B,H,S,D] bf16, 4M each
  short* Kp = Qp + (size_t)Mc * Ec;
  short* Vp = Kp + (size_t)Mc * Ec;
  short* ctx = Vp + (size_t)Mc * Ec;  // [M][E] bf16

  dim3 tb(256);
  dim3 gw(Ec / 32, Ec / 32);
  k_wt<<<gw, tb, 0, stream>>>(wq, wtq);
  k_wt<<<gw, tb, 0, stream>>>(wk, wtk);
  k_wt<<<gw, tb, 0, stream>>>(wv, wtv);
  k_wt<<<gw, tb, 0, stream>>>(wo, wto);

  dim3 gg(Ec / 128, Mc / 128);
  k_gemm<0><<<gg, tb, 0, stream>>>((const void*)q, wtq, bq, nullptr, (void*)Qp);
  k_gemm<0><<<gg, tb, 0, stream>>>((const void*)k, wtk, bk, nullptr, (void*)Kp);
  k_gemm<0><<<gg, tb, 0, stream>>>((const void*)v, wtv, bv, nullptr, (void*)Vp);

  dim3 ga(Sc / 64, Bc * Hc);
  k_attn<<<ga, tb, 0, stream>>>(Qp, Kp, Vp, maskp, ctx);

  k_gemm<1><<<gg, tb, 0, stream>>>((const void*)ctx, wto, bo, q, (void*)out);

  k_ln<<<dim3(Mc), tb, 0, stream>>>(out, gamma, beta);
}

// Round 2
// 217.564 us; speedup vs baseline: 1.4458x; 1.4458x over previous
//
#include <hip/hip_runtime.h>
#include <hip/hip_bf16.h>

typedef __bf16 bf16x8 __attribute__((ext_vector_type(8)));
typedef __attribute__((ext_vector_type(8))) short short8_t;
typedef __attribute__((ext_vector_type(4))) short short4_t;
typedef __attribute__((ext_vector_type(4))) float f32x4;

#define DEV __device__ __forceinline__

constexpr int Bc = 2, Sc = 2048, Ec = 1024, Hc = 16, Dc = 64;
constexpr int Mc = Bc * Sc;  // 4096
constexpr int NT = Sc / 64;  // 32 k-tiles

DEV short f2bf(float f) {
  unsigned int u = __builtin_bit_cast(unsigned int, f);
  unsigned int r = u + 0x7fffu + ((u >> 16) & 1u);
  return (short)(r >> 16);
}

DEV void gload16(const short* g, short* lds) {
  __builtin_amdgcn_global_load_lds((const __attribute__((address_space(1))) void*)g,
                                   (__attribute__((address_space(3))) void*)lds, 16, 0, 0);
}

// ---------- weight convert+transpose: w[K][N] f32 -> wt[N][K] bf16, 4 at once ----------
struct W4 { const float* w[4]; short* wt[4]; };
__global__ __launch_bounds__(256) void k_wt4(W4 a) {
  __shared__ float tile[32][33];
  const float* w = a.w[blockIdx.z];
  short* wt = a.wt[blockIdx.z];
  int bn = blockIdx.x, bk = blockIdx.y;
  int tx = threadIdx.x & 31, ty = threadIdx.x >> 5;
#pragma unroll
  for (int i = 0; i < 4; i++)
    tile[ty + i * 8][tx] = w[(size_t)(bk * 32 + ty + i * 8) * Ec + bn * 32 + tx];
  __syncthreads();
#pragma unroll
  for (int i = 0; i < 4; i++)
    wt[(size_t)(bn * 32 + ty + i * 8) * Ec + bk * 32 + tx] = f2bf(tile[tx][ty + i * 8]);
}

// ---------- QKV GEMM (merged z=3): C = A[M,K]f32 * Bt[N,K]^T + bias ----------
// z=0,1 -> out bf16 [B,H,S,D]; z=2 -> out bf16 [B,H,D,S] (pre-transposed V)
struct QKV3 { const float* A[3]; const short* Bt[3]; const float* bias[3]; short* out[3]; };

__global__ __launch_bounds__(256) void k_gemm_qkv(QKV3 args) {
  __shared__ short lA[128 * 64];
  __shared__ short lB[128 * 64];
  const int z = blockIdx.z;
  const float* A = args.A[z];
  const short* Bt = args.Bt[z];
  const float* bias = args.bias[z];
  short* out = args.out[z];
  const int t = threadIdx.x;
  const int m0 = blockIdx.y * 128, n0 = blockIdx.x * 128;
  const int lane = t & 63, wid = t >> 6;
  const int wm = wid >> 1, wn = wid & 1;
  const int rl = lane >> 3, chs = ((lane & 7) ^ (lane >> 3)) << 3;

  f32x4 acc[4][4];
#pragma unroll
  for (int i = 0; i < 4; i++)
#pragma unroll
    for (int j = 0; j < 4; j++) acc[i][j] = {0.f, 0.f, 0.f, 0.f};

  for (int k0 = 0; k0 < Ec; k0 += 64) {
    // B: async global->LDS, pre-swizzled source (linear LDS dest)
#pragma unroll
    for (int j = 0; j < 4; j++) {
      int r0 = wid * 32 + j * 8;
      gload16(Bt + (size_t)(n0 + r0 + rl) * Ec + k0 + chs, &lB[r0 * 64]);
    }
    // A: reg-staged fp32 -> bf16 convert, swizzled write
#pragma unroll
    for (int i = 0; i < 8; i++) {
      int row = i * 16 + (t >> 4);
      int c4 = (t & 15) * 4;
      float4 v = *(const float4*)(A + (size_t)(m0 + row) * Ec + k0 + c4);
      short4_t h;
      h[0] = f2bf(v.x); h[1] = f2bf(v.y); h[2] = f2bf(v.z); h[3] = f2bf(v.w);
      int chunk = (t & 15) >> 1, jo = (t & 1) * 4;
      *(short4_t*)&lA[row * 64 + ((chunk ^ (row & 7)) << 3) + jo] = h;
    }
    __syncthreads();
#pragma unroll
    for (int kc = 0; kc < 2; kc++) {
      bf16x8 a[4], b[4];
#pragma unroll
      for (int mf = 0; mf < 4; mf++) {
        int row = wm * 64 + mf * 16 + (lane & 15);
        int ch = (kc * 4 + (lane >> 4)) ^ (row & 7);
        a[mf] = *(const bf16x8*)&lA[row * 64 + (ch << 3)];
      }
#pragma unroll
      for (int nf = 0; nf < 4; nf++) {
        int row = wn * 64 + nf * 16 + (lane & 15);
        int ch = (kc * 4 + (lane >> 4)) ^ (row & 7);
        b[nf] = *(const bf16x8*)&lB[row * 64 + (ch << 3)];
      }
#pragma unroll
      for (int mf = 0; mf < 4; mf++)
#pragma unroll
        for (int nf = 0; nf < 4; nf++)
          acc[mf][nf] = __builtin_amdgcn_mfma_f32_16x16x32_bf16(a[mf], b[nf], acc[mf][nf], 0, 0, 0);
    }
    __syncthreads();
  }
  // epilogue
  const bool vT = (z == 2);
#pragma unroll
  for (int mf = 0; mf < 4; mf++) {
#pragma unroll
    for (int nf = 0; nf < 4; nf++) {
      int col = n0 + wn * 64 + nf * 16 + (lane & 15);
      float bs = bias[col];
      int row0 = m0 + wm * 64 + mf * 16 + ((lane >> 4) << 2);
      if (!vT) {
#pragma unroll
        for (int r = 0; r < 4; r++) {
          int row = row0 + r;
          size_t off = (((size_t)(row >> 11) * Hc + (col >> 6)) * Sc + (row & 2047)) * Dc + (col & 63);
          out[off] = f2bf(acc[mf][nf][r] + bs);
        }
      } else {
        short4_t h;
#pragma unroll
        for (int r = 0; r < 4; r++) h[r] = f2bf(acc[mf][nf][r] + bs);
        size_t off = (((size_t)(row0 >> 11) * Hc + (col >> 6)) * Dc + (col & 63)) * Sc + (row0 & 2047);
        *(short4_t*)&out[off] = h;
      }
    }
  }
}

// ---------- out-proj GEMM: fp32 out = ctx[M,K]bf16 * Bt^T + bias + residual ----------
__global__ __launch_bounds__(256) void k_gemm_o(const short* __restrict__ A,
                                                const short* __restrict__ Bt,
                                                const float* __restrict__ bias,
                                                const float* __restrict__ res,
                                                float* __restrict__ out) {
  __shared__ short lA[128 * 64];
  __shared__ short lB[128 * 64];
  const int t = threadIdx.x;
  const int m0 = blockIdx.y * 128, n0 = blockIdx.x * 128;
  const int lane = t & 63, wid = t >> 6;
  const int wm = wid >> 1, wn = wid & 1;
  const int rl = lane >> 3, chs = ((lane & 7) ^ (lane >> 3)) << 3;

  f32x4 acc[4][4];
#pragma unroll
  for (int i = 0; i < 4; i++)
#pragma unroll
    for (int j = 0; j < 4; j++) acc[i][j] = {0.f, 0.f, 0.f, 0.f};

  for (int k0 = 0; k0 < Ec; k0 += 64) {
#pragma unroll
    for (int j = 0; j < 4; j++) {
      int r0 = wid * 32 + j * 8;
      gload16(A + (size_t)(m0 + r0 + rl) * Ec + k0 + chs, &lA[r0 * 64]);
      gload16(Bt + (size_t)(n0 + r0 + rl) * Ec + k0 + chs, &lB[r0 * 64]);
    }
    __syncthreads();
#pragma unroll
    for (int kc = 0; kc < 2; kc++) {
      bf16x8 a[4], b[4];
#pragma unroll
      for (int mf = 0; mf < 4; mf++) {
        int row = wm * 64 + mf * 16 + (lane & 15);
        int ch = (kc * 4 + (lane >> 4)) ^ (row & 7);
        a[mf] = *(const bf16x8*)&lA[row * 64 + (ch << 3)];
      }
#pragma unroll
      for (int nf = 0; nf < 4; nf++) {
        int row = wn * 64 + nf * 16 + (lane & 15);
        int ch = (kc * 4 + (lane >> 4)) ^ (row & 7);
        b[nf] = *(const bf16x8*)&lB[row * 64 + (ch << 3)];
      }
#pragma unroll
      for (int mf = 0; mf < 4; mf++)
#pragma unroll
        for (int nf = 0; nf < 4; nf++)
          acc[mf][nf] = __builtin_amdgcn_mfma_f32_16x16x32_bf16(a[mf], b[nf], acc[mf][nf], 0, 0, 0);
    }
    __syncthreads();
  }
#pragma unroll
  for (int mf = 0; mf < 4; mf++) {
#pragma unroll
    for (int nf = 0; nf < 4; nf++) {
      int col = n0 + wn * 64 + nf * 16 + (lane & 15);
      float bs = bias[col];
#pragma unroll
      for (int r = 0; r < 4; r++) {
        int row = m0 + wm * 64 + mf * 16 + ((lane >> 4) << 2) + r;
        out[(size_t)row * Ec + col] = acc[mf][nf][r] + bs + res[(size_t)row * Ec + col];
      }
    }
  }
}

// ---------- flash attention, paired q-tiles (qi, 31-qi), dbuf K/V via global_load_lds ----------
DEV void sm_tile(f32x4* sacc, f32x4* oacc, float* rowm, float* rowl, short* lP,
                 int w, int lane, int qt, int koff, bool diag, float inv) {
  const int mb = w * 16 + ((lane >> 4) << 2);
  const int qg0 = qt * 64 + mb;
#pragma unroll
  for (int r = 0; r < 4; r++) {
    float sv[4];
    float mx = -INFINITY;
#pragma unroll
    for (int nf = 0; nf < 4; nf++) {
      float s = sacc[nf][r] * inv;
      if (diag && (koff + nf * 16 + (lane & 15)) > (qg0 + r)) s = -INFINITY;
      sv[nf] = s;
      mx = fmaxf(mx, s);
    }
    mx = fmaxf(mx, __shfl_xor(mx, 1));
    mx = fmaxf(mx, __shfl_xor(mx, 2));
    mx = fmaxf(mx, __shfl_xor(mx, 4));
    mx = fmaxf(mx, __shfl_xor(mx, 8));
    float mn = fmaxf(rowm[r], mx);
    float corr = exp2f((rowm[r] - mn) * 1.44269504f);
    rowm[r] = mn;
    float rs = 0.f;
    int m = mb + r;
#pragma unroll
    for (int nf = 0; nf < 4; nf++) {
      float p = exp2f((sv[nf] - mn) * 1.44269504f);
      rs += p;
      int col = nf * 16 + (lane & 15);
      lP[m * 64 + (((col >> 3) ^ (m & 7)) << 3) + (col & 7)] = f2bf(p);
    }
    rs += __shfl_xor(rs, 1);
    rs += __shfl_xor(rs, 2);
    rs += __shfl_xor(rs, 4);
    rs += __shfl_xor(rs, 8);
    rowl[r] = rowl[r] * corr + rs;
#pragma unroll
    for (int df = 0; df < 4; df++) oacc[df][r] *= corr;
  }
}

__global__ __launch_bounds__(256) void k_attn2(const short* __restrict__ Qp,
                                               const short* __restrict__ Kp,
                                               const short* __restrict__ Vt,
                                               const int* __restrict__ maskp,
                                               short* __restrict__ ctx) {
  __shared__ short lK[2][64 * 64];
  __shared__ short lV[2][64 * 64];
  __shared__ short lP[2][64 * 64];
  const int t = threadIdx.x, lane = t & 63, w = t >> 6;
  const int qi = blockIdx.x, bh = blockIdx.y;
  const bool causal = maskp[0] != 0;
  const int b = bh >> 4, h = bh & 15;
  const size_t base = (size_t)bh * Sc * Dc;
  const int qtA = qi, qtB = NT - 1 - qi;
  const int ktmax = causal ? qtB : (NT - 1);
  const float inv = 1.0f / (8.0f + 1e-8f);

  bf16x8 aqA[2], aqB[2];
  {
    int qrA = qtA * 64 + w * 16 + (lane & 15);
    int qrB = qtB * 64 + w * 16 + (lane & 15);
#pragma unroll
    for (int kc = 0; kc < 2; kc++) {
      aqA[kc] = *(const bf16x8*)(Qp + base + (size_t)qrA * Dc + kc * 32 + ((lane >> 4) << 3));
      aqB[kc] = *(const bf16x8*)(Qp + base + (size_t)qrB * Dc + kc * 32 + ((lane >> 4) << 3));
    }
  }
  f32x4 oA[4], oB[4];
  float mA[4], lAs[4], mB[4], lBs[4];
#pragma unroll
  for (int i = 0; i < 4; i++) {
    oA[i] = {0.f, 0.f, 0.f, 0.f};
    oB[i] = {0.f, 0.f, 0.f, 0.f};
  }
#pragma unroll
  for (int r = 0; r < 4; r++) {
    mA[r] = -INFINITY; lAs[r] = 0.f;
    mB[r] = -INFINITY; lBs[r] = 0.f;
  }

  const int rl = lane >> 3, chs = ((lane & 7) ^ (lane >> 3)) << 3;
  auto stage = [&](int kt_, int buf) {
    int koff = kt_ * 64;
#pragma unroll
    for (int j = 0; j < 2; j++) {
      int r0 = w * 16 + j * 8;
      gload16(Kp + base + (size_t)(koff + r0 + rl) * Dc + chs, &lK[buf][r0 * 64]);
      gload16(Vt + base + (size_t)(r0 + rl) * Sc + koff + chs, &lV[buf][r0 * 64]);
    }
  };

  stage(0, 0);
  __syncthreads();

  for (int kt = 0; kt <= ktmax; kt++) {
    const int cur = kt & 1;
    const int koff = kt * 64;
    if (kt < ktmax) stage(kt + 1, cur ^ 1);
    const bool actA = causal ? (kt <= qtA) : true;

    // QK^T (K fragments shared between both q-tiles)
    f32x4 sA[4], sB[4];
#pragma unroll
    for (int nf = 0; nf < 4; nf++) {
      sA[nf] = {0.f, 0.f, 0.f, 0.f};
      sB[nf] = {0.f, 0.f, 0.f, 0.f};
    }
#pragma unroll
    for (int kc = 0; kc < 2; kc++) {
#pragma unroll
      for (int nf = 0; nf < 4; nf++) {
        int row = nf * 16 + (lane & 15);
        int ch = (kc * 4 + (lane >> 4)) ^ (row & 7);
        bf16x8 bk = *(const bf16x8*)&lK[cur][row * 64 + (ch << 3)];
        sB[nf] = __builtin_amdgcn_mfma_f32_16x16x32_bf16(aqB[kc], bk, sB[nf], 0, 0, 0);
        if (actA) sA[nf] = __builtin_amdgcn_mfma_f32_16x16x32_bf16(aqA[kc], bk, sA[nf], 0, 0, 0);
      }
    }
    // softmax + P writes (own-wave rows only; no cross-wave barrier needed)
    sm_tile(sB, oB, mB, lBs, &lP[0][0], w, lane, qtB, koff, causal && (kt == qtB), inv);
    if (actA) sm_tile(sA, oA, mA, lAs, &lP[1][0], w, lane, qtA, koff, causal && (kt == qtA), inv);
    // PV (V fragments shared)
#pragma unroll
    for (int kc = 0; kc < 2; kc++) {
      int prow = w * 16 + (lane & 15);
      int ch = (kc * 4 + (lane >> 4)) ^ (prow & 7);
      bf16x8 apB = *(const bf16x8*)&lP[0][prow * 64 + (ch << 3)];
      bf16x8 apA = {};
      if (actA) apA = *(const bf16x8*)&lP[1][prow * 64 + (ch << 3)];
#pragma unroll
      for (int df = 0; df < 4; df++) {
        int vr = df * 16 + (lane & 15);
        int ch2 = (kc * 4 + (lane >> 4)) ^ (vr & 7);
        bf16x8 bv = *(const bf16x8*)&lV[cur][vr * 64 + (ch2 << 3)];
        oB[df] = __builtin_amdgcn_mfma_f32_16x16x32_bf16(apB, bv, oB[df], 0, 0, 0);
        if (actA) oA[df] = __builtin_amdgcn_mfma_f32_16x16x32_bf16(apA, bv, oA[df], 0, 0, 0);
      }
    }
    __syncthreads();  // waves done with buf[cur]; gloads into buf[cur^1] drained
  }

  const int mb = w * 16 + ((lane >> 4) << 2);
#pragma unroll
  for (int df = 0; df < 4; df++) {
#pragma unroll
    for (int r = 0; r < 4; r++) {
      int col = h * 64 + df * 16 + (lane & 15);
      int srA = qtA * 64 + mb + r;
      int srB = qtB * 64 + mb + r;
      ctx[(size_t)(b * Sc + srB) * Ec + col] = f2bf(oB[df][r] / lBs[r]);
      ctx[(size_t)(b * Sc + srA) * Ec + col] = f2bf(oA[df][r] / lAs[r]);
    }
  }
}

// ---------- LayerNorm in-place on fp32 [M][E] ----------
__global__ __launch_bounds__(256) void k_ln(float* __restrict__ x,
                                            const float* __restrict__ gamma,
                                            const float* __restrict__ beta) {
  int row = blockIdx.x, t = threadIdx.x;
  float4 v = *(const float4*)(x + (size_t)row * Ec + t * 4);
  float s = v.x + v.y + v.z + v.w;
  float sq = v.x * v.x + v.y * v.y + v.z * v.z + v.w * v.w;
#pragma unroll
  for (int m = 1; m < 64; m <<= 1) {
    s += __shfl_xor(s, m);
    sq += __shfl_xor(sq, m);
  }
  __shared__ float red[8];
  if ((t & 63) == 0) {
    red[t >> 6] = s;
    red[4 + (t >> 6)] = sq;
  }
  __syncthreads();
  s = red[0] + red[1] + red[2] + red[3];
  sq = red[4] + red[5] + red[6] + red[7];
  float mu = s * (1.f / Ec);
  float var = sq * (1.f / Ec) - mu * mu;
  float rstd = rsqrtf(var + 1e-5f);
  float4 g = *(const float4*)(gamma + t * 4);
  float4 bb = *(const float4*)(beta + t * 4);
  v.x = (v.x - mu) * rstd * g.x + bb.x;
  v.y = (v.y - mu) * rstd * g.y + bb.y;
  v.z = (v.z - mu) * rstd * g.z + bb.z;
  v.w = (v.w - mu) * rstd * g.w + bb.w;
  *(float4*)(x + (size_t)row * Ec + t * 4) = v;
}

extern "C" void kernel_launch(void* const* d_in, const int* in_sizes, int n_in,
                              void* d_out, int out_size, void* d_ws, size_t ws_size,
                              hipStream_t stream) {
  const float* q = (const float*)d_in[0];
  const float* k = (const float*)d_in[1];
  const float* v = (const float*)d_in[2];
  const float* wq = (const float*)d_in[3];
  const float* bq = (const float*)d_in[4];
  const float* wk = (const float*)d_in[5];
  const float* bk = (const float*)d_in[6];
  const float* wv = (const float*)d_in[7];
  const float* bv = (const float*)d_in[8];
  const float* wo = (const float*)d_in[9];
  const float* bo = (const float*)d_in[10];
  const float* gamma = (const float*)d_in[11];
  const float* beta = (const float*)d_in[12];
  const int* maskp = (const int*)d_in[13];
  float* out = (float*)d_out;

  short* wtq = (short*)d_ws;
  short* wtk = wtq + (size_t)Ec * Ec;
  short* wtv = wtk + (size_t)Ec * Ec;
  short* wto = wtv + (size_t)Ec * Ec;
  short* Qp = wto + (size_t)Ec * Ec;   // [B,H,S,D] bf16
  short* Kp = Qp + (size_t)Mc * Ec;    // [B,H,S,D] bf16
  short* Vt = Kp + (size_t)Mc * Ec;    // [B,H,D,S] bf16
  short* ctx = Vt + (size_t)Mc * Ec;   // [M][E] bf16

  dim3 tb(256);

  W4 wargs;
  wargs.w[0] = wq; wargs.w[1] = wk; wargs.w[2] = wv; wargs.w[3] = wo;
  wargs.wt[0] = wtq; wargs.wt[1] = wtk; wargs.wt[2] = wtv; wargs.wt[3] = wto;
  k_wt4<<<dim3(Ec / 32, Ec / 32, 4), tb, 0, stream>>>(wargs);

  QKV3 gargs;
  gargs.A[0] = q; gargs.A[1] = k; gargs.A[2] = v;
  gargs.Bt[0] = wtq; gargs.Bt[1] = wtk; gargs.Bt[2] = wtv;
  gargs.bias[0] = bq; gargs.bias[1] = bk; gargs.bias[2] = bv;
  gargs.out[0] = Qp; gargs.out[1] = Kp; gargs.out[2] = Vt;
  k_gemm_qkv<<<dim3(Ec / 128, Mc / 128, 3), tb, 0, stream>>>(gargs);

  k_attn2<<<dim3(NT / 2, Bc * Hc), tb, 0, stream>>>(Qp, Kp, Vt, maskp, ctx);

  k_gemm_o<<<dim3(Ec / 128, Mc / 128), tb, 0, stream>>>(ctx, wto, bo, q, out);

  k_ln<<<dim3(Mc), tb, 0, stream>>>(out, gamma, beta);
}

// Round 3
// 165.497 us; speedup vs baseline: 1.9007x; 1.3146x over previous
//
#include <hip/hip_runtime.h>
#include <hip/hip_bf16.h>

typedef __bf16 bf16x8 __attribute__((ext_vector_type(8)));
typedef __attribute__((ext_vector_type(8))) short short8_t;
typedef __attribute__((ext_vector_type(4))) short short4_t;
typedef __attribute__((ext_vector_type(4))) float f32x4;

#define DEV __device__ __forceinline__

constexpr int Bc = 2, Sc = 2048, Ec = 1024, Hc = 16, Dc = 64;
constexpr int Mc = Bc * Sc;  // 4096
constexpr int NT = Sc / 64;  // 32 k-tiles
// fold 1/(sqrt(D)+1e-8) and log2(e) into Q projection
constexpr float kQS = (float)((1.0 / (8.0 + 1e-8)) * 1.4426950408889634);

DEV short f2bf(float f) {
  unsigned int u = __builtin_bit_cast(unsigned int, f);
  unsigned int r = u + 0x7fffu + ((u >> 16) & 1u);
  return (short)(r >> 16);
}
DEV short bfc(float f) { __bf16 h = (__bf16)f; return __builtin_bit_cast(short, h); }

DEV void gload16(const short* g, short* lds) {
  __builtin_amdgcn_global_load_lds((const __attribute__((address_space(1))) void*)g,
                                   (__attribute__((address_space(3))) void*)lds, 16, 0, 0);
}

// ---------- weight convert+transpose: w[K][N] f32 -> wt[N][K] bf16, 4 at once ----------
struct W4 { const float* w[4]; short* wt[4]; };
__global__ __launch_bounds__(256) void k_wt4(W4 a) {
  __shared__ float tile[32][33];
  const float* w = a.w[blockIdx.z];
  short* wt = a.wt[blockIdx.z];
  int bn = blockIdx.x, bk = blockIdx.y;
  int tx = threadIdx.x & 31, ty = threadIdx.x >> 5;
#pragma unroll
  for (int i = 0; i < 4; i++)
    tile[ty + i * 8][tx] = w[(size_t)(bk * 32 + ty + i * 8) * Ec + bn * 32 + tx];
  __syncthreads();
#pragma unroll
  for (int i = 0; i < 4; i++)
    wt[(size_t)(bn * 32 + ty + i * 8) * Ec + bk * 32 + tx] = f2bf(tile[tx][ty + i * 8]);
}

// ---------- fp32 -> bf16 bulk convert (q,k,v) ----------
struct C3 { const float* x[3]; short* y[3]; };
__global__ __launch_bounds__(256) void k_cvt(C3 a) {
  const float* x = a.x[blockIdx.z];
  short* y = a.y[blockIdx.z];
  size_t i = ((size_t)blockIdx.x * 256 + threadIdx.x) * 8;
  float4 v0 = *(const float4*)(x + i);
  float4 v1 = *(const float4*)(x + i + 4);
  short8_t h;
  h[0] = bfc(v0.x); h[1] = bfc(v0.y); h[2] = bfc(v0.z); h[3] = bfc(v0.w);
  h[4] = bfc(v1.x); h[5] = bfc(v1.y); h[6] = bfc(v1.z); h[7] = bfc(v1.w);
  *(short8_t*)(y + i) = h;
}

// ---------- shared MFMA tile compute (128x128, BK=64) ----------
DEV void gemm_mfma(const short* lA, const short* lB, f32x4 (&acc)[4][4], int lane, int wm, int wn) {
#pragma unroll
  for (int kc = 0; kc < 2; kc++) {
    bf16x8 a[4], b[4];
#pragma unroll
    for (int mf = 0; mf < 4; mf++) {
      int row = wm * 64 + mf * 16 + (lane & 15);
      int ch = (kc * 4 + (lane >> 4)) ^ (row & 7);
      a[mf] = *(const bf16x8*)&lA[row * 64 + (ch << 3)];
    }
#pragma unroll
    for (int nf = 0; nf < 4; nf++) {
      int row = wn * 64 + nf * 16 + (lane & 15);
      int ch = (kc * 4 + (lane >> 4)) ^ (row & 7);
      b[nf] = *(const bf16x8*)&lB[row * 64 + (ch << 3)];
    }
#pragma unroll
    for (int mf = 0; mf < 4; mf++)
#pragma unroll
      for (int nf = 0; nf < 4; nf++)
        acc[mf][nf] = __builtin_amdgcn_mfma_f32_16x16x32_bf16(a[mf], b[nf], acc[mf][nf], 0, 0, 0);
  }
}

// ---------- QKV GEMM (z=3 merged, bf16 A, 2-phase dbuf) ----------
// z=0 -> Q [B,H,S,D] scaled by kQS; z=1 -> K [B,H,S,D]; z=2 -> V^T [B,H,D,S]
struct QKV3 { const short* A[3]; const short* Bt[3]; const float* bias[3]; short* out[3]; };

__global__ __launch_bounds__(256) void k_gemm_qkv(QKV3 args) {
  __shared__ short lA[2][128 * 64];
  __shared__ short lB[2][128 * 64];
  int lin = blockIdx.x + 8 * blockIdx.y + 256 * blockIdx.z;  // 768 blocks
  lin = (lin & 7) * 96 + (lin >> 3);                          // XCD-contiguous
  const int bx = lin & 7, by = (lin >> 3) & 31, z = lin >> 8;
  const short* A = args.A[z];
  const short* Bt = args.Bt[z];
  const float* bias = args.bias[z];
  short* out = args.out[z];
  const int t = threadIdx.x;
  const int m0 = by * 128, n0 = bx * 128;
  const int lane = t & 63, wid = t >> 6;
  const int wm = wid >> 1, wn = wid & 1;
  const int rl = lane >> 3, chs = ((lane & 7) ^ rl) << 3;

  f32x4 acc[4][4];
#pragma unroll
  for (int i = 0; i < 4; i++)
#pragma unroll
    for (int j = 0; j < 4; j++) acc[i][j] = {0.f, 0.f, 0.f, 0.f};

  auto stage = [&](int k0, int buf) {
#pragma unroll
    for (int j = 0; j < 4; j++) {
      int r0 = wid * 32 + j * 8;
      gload16(A + (size_t)(m0 + r0 + rl) * Ec + k0 + chs, &lA[buf][r0 * 64]);
      gload16(Bt + (size_t)(n0 + r0 + rl) * Ec + k0 + chs, &lB[buf][r0 * 64]);
    }
  };
  stage(0, 0);
  __syncthreads();
  int buf = 0;
  for (int s = 0; s < Ec / 64; s++) {
    if (s + 1 < Ec / 64) stage((s + 1) * 64, buf ^ 1);
    gemm_mfma(lA[buf], lB[buf], acc, lane, wm, wn);
    __syncthreads();
    buf ^= 1;
  }
  const float sc = (z == 0) ? kQS : 1.0f;
  const bool vT = (z == 2);
#pragma unroll
  for (int mf = 0; mf < 4; mf++) {
#pragma unroll
    for (int nf = 0; nf < 4; nf++) {
      int col = n0 + wn * 64 + nf * 16 + (lane & 15);
      float bs = bias[col];
      int row0 = m0 + wm * 64 + mf * 16 + ((lane >> 4) << 2);
      if (!vT) {
#pragma unroll
        for (int r = 0; r < 4; r++) {
          int row = row0 + r;
          size_t off = (((size_t)(row >> 11) * Hc + (col >> 6)) * Sc + (row & 2047)) * Dc + (col & 63);
          out[off] = f2bf((acc[mf][nf][r] + bs) * sc);
        }
      } else {
        short4_t h;
#pragma unroll
        for (int r = 0; r < 4; r++) h[r] = f2bf(acc[mf][nf][r] + bs);
        size_t off = (((size_t)(row0 >> 11) * Hc + (col >> 6)) * Dc + (col & 63)) * Sc + (row0 & 2047);
        *(short4_t*)&out[off] = h;
      }
    }
  }
}

// ---------- out-proj GEMM (2-phase dbuf): fp32 out = ctx*Wo^T + bias + residual ----------
__global__ __launch_bounds__(256) void k_gemm_o(const short* __restrict__ A,
                                                const short* __restrict__ Bt,
                                                const float* __restrict__ bias,
                                                const float* __restrict__ res,
                                                float* __restrict__ out) {
  __shared__ short lA[2][128 * 64];
  __shared__ short lB[2][128 * 64];
  int lin = blockIdx.x + 8 * blockIdx.y;  // 256 blocks
  lin = (lin & 7) * 32 + (lin >> 3);
  const int bx = lin & 7, by = lin >> 3;
  const int t = threadIdx.x;
  const int m0 = by * 128, n0 = bx * 128;
  const int lane = t & 63, wid = t >> 6;
  const int wm = wid >> 1, wn = wid & 1;
  const int rl = lane >> 3, chs = ((lane & 7) ^ rl) << 3;

  f32x4 acc[4][4];
#pragma unroll
  for (int i = 0; i < 4; i++)
#pragma unroll
    for (int j = 0; j < 4; j++) acc[i][j] = {0.f, 0.f, 0.f, 0.f};

  auto stage = [&](int k0, int buf) {
#pragma unroll
    for (int j = 0; j < 4; j++) {
      int r0 = wid * 32 + j * 8;
      gload16(A + (size_t)(m0 + r0 + rl) * Ec + k0 + chs, &lA[buf][r0 * 64]);
      gload16(Bt + (size_t)(n0 + r0 + rl) * Ec + k0 + chs, &lB[buf][r0 * 64]);
    }
  };
  stage(0, 0);
  __syncthreads();
  int buf = 0;
  for (int s = 0; s < Ec / 64; s++) {
    if (s + 1 < Ec / 64) stage((s + 1) * 64, buf ^ 1);
    gemm_mfma(lA[buf], lB[buf], acc, lane, wm, wn);
    __syncthreads();
    buf ^= 1;
  }
#pragma unroll
  for (int mf = 0; mf < 4; mf++) {
#pragma unroll
    for (int nf = 0; nf < 4; nf++) {
      int col = n0 + wn * 64 + nf * 16 + (lane & 15);
      float bs = bias[col];
#pragma unroll
      for (int r = 0; r < 4; r++) {
        int row = m0 + wm * 64 + mf * 16 + ((lane >> 4) << 2) + r;
        out[(size_t)row * Ec + col] = acc[mf][nf][r] + bs + res[(size_t)row * Ec + col];
      }
    }
  }
}

// ---------- flash attention, swapped-QK^T row-local softmax, no max-tracking ----------
DEV void smstore(const f32x4 (&s)[4], float& lsum, short* lPbuf,
                 int w, int lane, bool diag, int qg, int koff) {
  const int gs = lane >> 4, l15 = lane & 15;
  const int m = w * 16 + l15;
  float psum = 0.f;
#pragma unroll
  for (int mf = 0; mf < 4; mf++) {
    short4_t h;
#pragma unroll
    for (int r = 0; r < 4; r++) {
      float p = exp2f(s[mf][r]);
      if (diag && (koff + mf * 16 + gs * 4 + r) > qg) p = 0.f;
      psum += p;
      h[r] = bfc(p);
    }
    int c = (2 * mf + (gs >> 1)) ^ (m & 7);
    *(short4_t*)&lPbuf[m * 64 + (c << 3) + (gs & 1) * 4] = h;
  }
  psum += __shfl_xor(psum, 16);
  psum += __shfl_xor(psum, 32);
  lsum += psum;
}

__global__ __launch_bounds__(256) void k_attn3(const short* __restrict__ Qp,
                                               const short* __restrict__ Kp,
                                               const short* __restrict__ Vt,
                                               const int* __restrict__ maskp,
                                               short* __restrict__ ctx) {
  __shared__ short lK[2][4096];
  __shared__ short lV[2][4096];
  __shared__ short lP[2][4096];
  int lin = blockIdx.x + 16 * blockIdx.y;  // 512 blocks
  lin = (lin & 7) * 64 + (lin >> 3);       // XCD-contiguous
  const int qi = lin & 15, bh = lin >> 4;
  const int t = threadIdx.x, lane = t & 63, w = t >> 6;
  const int gs = lane >> 4, l15 = lane & 15;
  const bool causal = maskp[0] != 0;
  const int b = bh >> 4, h = bh & 15;
  const size_t base = (size_t)bh * Sc * Dc;
  const int qtA = qi, qtB = NT - 1 - qi;
  const int ktmax = causal ? qtB : (NT - 1);

  bf16x8 aqA[2], aqB[2];
  {
    int qrA = qtA * 64 + w * 16 + l15;
    int qrB = qtB * 64 + w * 16 + l15;
#pragma unroll
    for (int kc = 0; kc < 2; kc++) {
      aqA[kc] = *(const bf16x8*)(Qp + base + (size_t)qrA * Dc + kc * 32 + (gs << 3));
      aqB[kc] = *(const bf16x8*)(Qp + base + (size_t)qrB * Dc + kc * 32 + (gs << 3));
    }
  }
  f32x4 oA[4], oB[4];
#pragma unroll
  for (int i = 0; i < 4; i++) {
    oA[i] = {0.f, 0.f, 0.f, 0.f};
    oB[i] = {0.f, 0.f, 0.f, 0.f};
  }
  float lsA = 0.f, lsB = 0.f;

  const int rl = lane >> 3, chs = ((lane & 7) ^ rl) << 3;
  auto stage = [&](int kt_, int buf) {
    int koff = kt_ * 64;
#pragma unroll
    for (int j = 0; j < 2; j++) {
      int r0 = w * 16 + j * 8;
      gload16(Kp + base + (size_t)(koff + r0 + rl) * Dc + chs, &lK[buf][r0 * 64]);
      gload16(Vt + base + (size_t)(r0 + rl) * Sc + koff + chs, &lV[buf][r0 * 64]);
    }
  };
  stage(0, 0);
  __syncthreads();

  const int qgA = qtA * 64 + w * 16 + l15;
  const int qgB = qtB * 64 + w * 16 + l15;

  for (int kt = 0; kt <= ktmax; kt++) {
    const int cur = kt & 1, koff = kt * 64;
    if (kt < ktmax) stage(kt + 1, cur ^ 1);
    const bool actA = !causal || (kt <= qtA);

    // S^T = K Q^T (swapped): lane holds q=lane&15, k rows in regs
    f32x4 sA[4], sB[4];
#pragma unroll
    for (int mf = 0; mf < 4; mf++) {
      sA[mf] = {0.f, 0.f, 0.f, 0.f};
      sB[mf] = {0.f, 0.f, 0.f, 0.f};
    }
#pragma unroll
    for (int kc = 0; kc < 2; kc++) {
#pragma unroll
      for (int mf = 0; mf < 4; mf++) {
        int row = mf * 16 + l15;
        int ch = (kc * 4 + gs) ^ (row & 7);
        bf16x8 bk = *(const bf16x8*)&lK[cur][row * 64 + (ch << 3)];
        sB[mf] = __builtin_amdgcn_mfma_f32_16x16x32_bf16(bk, aqB[kc], sB[mf], 0, 0, 0);
        if (actA) sA[mf] = __builtin_amdgcn_mfma_f32_16x16x32_bf16(bk, aqA[kc], sA[mf], 0, 0, 0);
      }
    }
    smstore(sB, lsB, lP[0], w, lane, causal && (kt == qtB), qgB, koff);
    if (actA) smstore(sA, lsA, lP[1], w, lane, causal && (kt == qtA), qgA, koff);

    // O += P V (A=P rows=q, B=V^T rows=d)
#pragma unroll
    for (int kc = 0; kc < 2; kc++) {
      int prow = w * 16 + l15;
      int ch = (kc * 4 + gs) ^ (prow & 7);
      bf16x8 apB = *(const bf16x8*)&lP[0][prow * 64 + (ch << 3)];
      bf16x8 apA = {};
      if (actA) apA = *(const bf16x8*)&lP[1][prow * 64 + (ch << 3)];
#pragma unroll
      for (int df = 0; df < 4; df++) {
        int vr = df * 16 + l15;
        int ch2 = (kc * 4 + gs) ^ (vr & 7);
        bf16x8 bv = *(const bf16x8*)&lV[cur][vr * 64 + (ch2 << 3)];
        oB[df] = __builtin_amdgcn_mfma_f32_16x16x32_bf16(apB, bv, oB[df], 0, 0, 0);
        if (actA) oA[df] = __builtin_amdgcn_mfma_f32_16x16x32_bf16(apA, bv, oA[df], 0, 0, 0);
      }
    }
    __syncthreads();
  }

#pragma unroll
  for (int r = 0; r < 4; r++) {
    float ib = 1.0f / __shfl(lsB, (gs << 2) + r);
    float ia = 1.0f / __shfl(lsA, (gs << 2) + r);
    int srB = qtB * 64 + w * 16 + (gs << 2) + r;
    int srA = qtA * 64 + w * 16 + (gs << 2) + r;
#pragma unroll
    for (int df = 0; df < 4; df++) {
      int col = h * 64 + df * 16 + l15;
      ctx[(size_t)(b * Sc + srB) * Ec + col] = f2bf(oB[df][r] * ib);
      ctx[(size_t)(b * Sc + srA) * Ec + col] = f2bf(oA[df][r] * ia);
    }
  }
}

// ---------- LayerNorm in-place on fp32 [M][E] ----------
__global__ __launch_bounds__(256) void k_ln(float* __restrict__ x,
                                            const float* __restrict__ gamma,
                                            const float* __restrict__ beta) {
  int row = blockIdx.x, t = threadIdx.x;
  float4 v = *(const float4*)(x + (size_t)row * Ec + t * 4);
  float s = v.x + v.y + v.z + v.w;
  float sq = v.x * v.x + v.y * v.y + v.z * v.z + v.w * v.w;
#pragma unroll
  for (int m = 1; m < 64; m <<= 1) {
    s += __shfl_xor(s, m);
    sq += __shfl_xor(sq, m);
  }
  __shared__ float red[8];
  if ((t & 63) == 0) {
    red[t >> 6] = s;
    red[4 + (t >> 6)] = sq;
  }
  __syncthreads();
  s = red[0] + red[1] + red[2] + red[3];
  sq = red[4] + red[5] + red[6] + red[7];
  float mu = s * (1.f / Ec);
  float var = sq * (1.f / Ec) - mu * mu;
  float rstd = rsqrtf(var + 1e-5f);
  float4 g = *(const float4*)(gamma + t * 4);
  float4 bb = *(const float4*)(beta + t * 4);
  v.x = (v.x - mu) * rstd * g.x + bb.x;
  v.y = (v.y - mu) * rstd * g.y + bb.y;
  v.z = (v.z - mu) * rstd * g.z + bb.z;
  v.w = (v.w - mu) * rstd * g.w + bb.w;
  *(float4*)(x + (size_t)row * Ec + t * 4) = v;
}

extern "C" void kernel_launch(void* const* d_in, const int* in_sizes, int n_in,
                              void* d_out, int out_size, void* d_ws, size_t ws_size,
                              hipStream_t stream) {
  const float* q = (const float*)d_in[0];
  const float* k = (const float*)d_in[1];
  const float* v = (const float*)d_in[2];
  const float* wq = (const float*)d_in[3];
  const float* bq = (const float*)d_in[4];
  const float* wk = (const float*)d_in[5];
  const float* bk = (const float*)d_in[6];
  const float* wv = (const float*)d_in[7];
  const float* bv = (const float*)d_in[8];
  const float* wo = (const float*)d_in[9];
  const float* bo = (const float*)d_in[10];
  const float* gamma = (const float*)d_in[11];
  const float* beta = (const float*)d_in[12];
  const int* maskp = (const int*)d_in[13];
  float* out = (float*)d_out;

  // workspace: 8MB weights + 24MB QKV + 8MB ctx = 40MB
  short* wtq = (short*)d_ws;
  short* wtk = wtq + (size_t)Ec * Ec;
  short* wtv = wtk + (size_t)Ec * Ec;
  short* wto = wtv + (size_t)Ec * Ec;
  short* Qp = wto + (size_t)Ec * Ec;   // [B,H,S,D] bf16 (pre-scaled)
  short* Kp = Qp + (size_t)Mc * Ec;    // [B,H,S,D] bf16
  short* Vt = Kp + (size_t)Mc * Ec;    // [B,H,D,S] bf16
  short* ctx = Vt + (size_t)Mc * Ec;   // [M][E] bf16

  // bf16 copies of q,k,v live in d_out (dead until k_gemm_o) + ctx slot
  short* xq = (short*)d_out;
  short* xk = xq + (size_t)Mc * Ec;
  short* xv = ctx;

  dim3 tb(256);

  W4 wargs;
  wargs.w[0] = wq; wargs.w[1] = wk; wargs.w[2] = wv; wargs.w[3] = wo;
  wargs.wt[0] = wtq; wargs.wt[1] = wtk; wargs.wt[2] = wtv; wargs.wt[3] = wto;
  k_wt4<<<dim3(Ec / 32, Ec / 32, 4), tb, 0, stream>>>(wargs);

  C3 cargs;
  cargs.x[0] = q; cargs.x[1] = k; cargs.x[2] = v;
  cargs.y[0] = xq; cargs.y[1] = xk; cargs.y[2] = xv;
  k_cvt<<<dim3(Mc * Ec / 2048, 1, 3), tb, 0, stream>>>(cargs);

  QKV3 gargs;
  gargs.A[0] = xq; gargs.A[1] = xk; gargs.A[2] = xv;
  gargs.Bt[0] = wtq; gargs.Bt[1] = wtk; gargs.Bt[2] = wtv;
  gargs.bias[0] = bq; gargs.bias[1] = bk; gargs.bias[2] = bv;
  gargs.out[0] = Qp; gargs.out[1] = Kp; gargs.out[2] = Vt;
  k_gemm_qkv<<<dim3(Ec / 128, Mc / 128, 3), tb, 0, stream>>>(gargs);

  k_attn3<<<dim3(NT / 2, Bc * Hc), tb, 0, stream>>>(Qp, Kp, Vt, maskp, ctx);

  k_gemm_o<<<dim3(Ec / 128, Mc / 128), tb, 0, stream>>>(ctx, wto, bo, q, out);

  k_ln<<<dim3(Mc), tb, 0, stream>>>(out, gamma, beta);
}

// Round 4
// 159.538 us; speedup vs baseline: 1.9717x; 1.0374x over previous
//
#include <hip/hip_runtime.h>
#include <hip/hip_bf16.h>

typedef __bf16 bf16x8 __attribute__((ext_vector_type(8)));
typedef __attribute__((ext_vector_type(8))) short short8_t;
typedef __attribute__((ext_vector_type(4))) short short4_t;
typedef __attribute__((ext_vector_type(4))) float f32x4;

#define DEV __device__ __forceinline__

constexpr int Bc = 2, Sc = 2048, Ec = 1024, Hc = 16, Dc = 64;
constexpr int Mc = Bc * Sc;  // 4096
constexpr int NT = Sc / 64;  // 32 k-tiles
// fold 1/(sqrt(D)+1e-8) and log2(e) into Q projection
constexpr float kQS = (float)((1.0 / (8.0 + 1e-8)) * 1.4426950408889634);

DEV short f2bf(float f) {
  unsigned int u = __builtin_bit_cast(unsigned int, f);
  unsigned int r = u + 0x7fffu + ((u >> 16) & 1u);
  return (short)(r >> 16);
}
DEV short bfc(float f) { __bf16 h = (__bf16)f; return __builtin_bit_cast(short, h); }

// single-instruction 2^x (exp2f without fast-math goes through the OCML
// precision path, ~15-20 VALU instrs -- that was 60% of the attn kernel)
DEV float fexp2(float x) {
#if __has_builtin(__builtin_amdgcn_exp2f)
  return __builtin_amdgcn_exp2f(x);
#else
  float r;
  asm("v_exp_f32 %0, %1" : "=v"(r) : "v"(x));
  return r;
#endif
}

DEV void gload16(const short* g, short* lds) {
  __builtin_amdgcn_global_load_lds((const __attribute__((address_space(1))) void*)g,
                                   (__attribute__((address_space(3))) void*)lds, 16, 0, 0);
}

// ---------- merged prep: 4x weight transpose->bf16 + 3x fp32->bf16 convert ----------
struct Prep {
  const float* w[4]; short* wt[4];
  const float* x[3]; short* y[3];
};
__global__ __launch_bounds__(256) void k_prep(Prep a) {
  const int bid = blockIdx.x;
  if (bid < 4096) {  // weight convert+transpose: w[K][N] f32 -> wt[N][K] bf16
    __shared__ float tile[32][33];
    const int z = bid >> 10, bk = (bid >> 5) & 31, bn = bid & 31;
    const float* w = a.w[z];
    short* wt = a.wt[z];
    int tx = threadIdx.x & 31, ty = threadIdx.x >> 5;
#pragma unroll
    for (int i = 0; i < 4; i++)
      tile[ty + i * 8][tx] = w[(size_t)(bk * 32 + ty + i * 8) * Ec + bn * 32 + tx];
    __syncthreads();
#pragma unroll
    for (int i = 0; i < 4; i++)
      wt[(size_t)(bn * 32 + ty + i * 8) * Ec + bk * 32 + tx] = f2bf(tile[tx][ty + i * 8]);
  } else {  // bulk fp32 -> bf16
    const int idx = bid - 4096;
    const int z = idx >> 11, c = idx & 2047;
    const float* x = a.x[z];
    short* y = a.y[z];
    size_t i = ((size_t)c * 256 + threadIdx.x) * 8;
    float4 v0 = *(const float4*)(x + i);
    float4 v1 = *(const float4*)(x + i + 4);
    short8_t h;
    h[0] = bfc(v0.x); h[1] = bfc(v0.y); h[2] = bfc(v0.z); h[3] = bfc(v0.w);
    h[4] = bfc(v1.x); h[5] = bfc(v1.y); h[6] = bfc(v1.z); h[7] = bfc(v1.w);
    *(short8_t*)(y + i) = h;
  }
}

// ---------- shared MFMA tile compute (128x128, BK=64) ----------
DEV void gemm_mfma(const short* lA, const short* lB, f32x4 (&acc)[4][4], int lane, int wm, int wn) {
#pragma unroll
  for (int kc = 0; kc < 2; kc++) {
    bf16x8 a[4], b[4];
#pragma unroll
    for (int mf = 0; mf < 4; mf++) {
      int row = wm * 64 + mf * 16 + (lane & 15);
      int ch = (kc * 4 + (lane >> 4)) ^ (row & 7);
      a[mf] = *(const bf16x8*)&lA[row * 64 + (ch << 3)];
    }
#pragma unroll
    for (int nf = 0; nf < 4; nf++) {
      int row = wn * 64 + nf * 16 + (lane & 15);
      int ch = (kc * 4 + (lane >> 4)) ^ (row & 7);
      b[nf] = *(const bf16x8*)&lB[row * 64 + (ch << 3)];
    }
#pragma unroll
    for (int mf = 0; mf < 4; mf++)
#pragma unroll
      for (int nf = 0; nf < 4; nf++)
        acc[mf][nf] = __builtin_amdgcn_mfma_f32_16x16x32_bf16(a[mf], b[nf], acc[mf][nf], 0, 0, 0);
  }
}

// ---------- QKV GEMM (z=3 merged, bf16 A, 2-phase dbuf) ----------
// z=0 -> Q [B,H,S,D] scaled by kQS; z=1 -> K [B,H,S,D]; z=2 -> V^T [B,H,D,S]
struct QKV3 { const short* A[3]; const short* Bt[3]; const float* bias[3]; short* out[3]; };

__global__ __launch_bounds__(256) void k_gemm_qkv(QKV3 args) {
  __shared__ short lA[2][128 * 64];
  __shared__ short lB[2][128 * 64];
  int lin = blockIdx.x + 8 * blockIdx.y + 256 * blockIdx.z;  // 768 blocks
  lin = (lin & 7) * 96 + (lin >> 3);                          // XCD-contiguous
  const int bx = lin & 7, by = (lin >> 3) & 31, z = lin >> 8;
  const short* A = args.A[z];
  const short* Bt = args.Bt[z];
  const float* bias = args.bias[z];
  short* out = args.out[z];
  const int t = threadIdx.x;
  const int m0 = by * 128, n0 = bx * 128;
  const int lane = t & 63, wid = t >> 6;
  const int wm = wid >> 1, wn = wid & 1;
  const int rl = lane >> 3, chs = ((lane & 7) ^ rl) << 3;

  f32x4 acc[4][4];
#pragma unroll
  for (int i = 0; i < 4; i++)
#pragma unroll
    for (int j = 0; j < 4; j++) acc[i][j] = {0.f, 0.f, 0.f, 0.f};

  auto stage = [&](int k0, int buf) {
#pragma unroll
    for (int j = 0; j < 4; j++) {
      int r0 = wid * 32 + j * 8;
      gload16(A + (size_t)(m0 + r0 + rl) * Ec + k0 + chs, &lA[buf][r0 * 64]);
      gload16(Bt + (size_t)(n0 + r0 + rl) * Ec + k0 + chs, &lB[buf][r0 * 64]);
    }
  };
  stage(0, 0);
  __syncthreads();
  int buf = 0;
  for (int s = 0; s < Ec / 64; s++) {
    if (s + 1 < Ec / 64) stage((s + 1) * 64, buf ^ 1);
    gemm_mfma(lA[buf], lB[buf], acc, lane, wm, wn);
    __syncthreads();
    buf ^= 1;
  }
  const float sc = (z == 0) ? kQS : 1.0f;
  const bool vT = (z == 2);
#pragma unroll
  for (int mf = 0; mf < 4; mf++) {
#pragma unroll
    for (int nf = 0; nf < 4; nf++) {
      int col = n0 + wn * 64 + nf * 16 + (lane & 15);
      float bs = bias[col];
      int row0 = m0 + wm * 64 + mf * 16 + ((lane >> 4) << 2);
      if (!vT) {
#pragma unroll
        for (int r = 0; r < 4; r++) {
          int row = row0 + r;
          size_t off = (((size_t)(row >> 11) * Hc + (col >> 6)) * Sc + (row & 2047)) * Dc + (col & 63);
          out[off] = f2bf((acc[mf][nf][r] + bs) * sc);
        }
      } else {
        short4_t h;
#pragma unroll
        for (int r = 0; r < 4; r++) h[r] = f2bf(acc[mf][nf][r] + bs);
        size_t off = (((size_t)(row0 >> 11) * Hc + (col >> 6)) * Dc + (col & 63)) * Sc + (row0 & 2047);
        *(short4_t*)&out[off] = h;
      }
    }
  }
}

// ---------- out-proj GEMM (2-phase dbuf): fp32 out = ctx*Wo^T + bias + residual ----------
__global__ __launch_bounds__(256) void k_gemm_o(const short* __restrict__ A,
                                                const short* __restrict__ Bt,
                                                const float* __restrict__ bias,
                                                const float* __restrict__ res,
                                                float* __restrict__ out) {
  __shared__ short lA[2][128 * 64];
  __shared__ short lB[2][128 * 64];
  int lin = blockIdx.x + 8 * blockIdx.y;  // 256 blocks
  lin = (lin & 7) * 32 + (lin >> 3);
  const int bx = lin & 7, by = lin >> 3;
  const int t = threadIdx.x;
  const int m0 = by * 128, n0 = bx * 128;
  const int lane = t & 63, wid = t >> 6;
  const int wm = wid >> 1, wn = wid & 1;
  const int rl = lane >> 3, chs = ((lane & 7) ^ rl) << 3;

  f32x4 acc[4][4];
#pragma unroll
  for (int i = 0; i < 4; i++)
#pragma unroll
    for (int j = 0; j < 4; j++) acc[i][j] = {0.f, 0.f, 0.f, 0.f};

  auto stage = [&](int k0, int buf) {
#pragma unroll
    for (int j = 0; j < 4; j++) {
      int r0 = wid * 32 + j * 8;
      gload16(A + (size_t)(m0 + r0 + rl) * Ec + k0 + chs, &lA[buf][r0 * 64]);
      gload16(Bt + (size_t)(n0 + r0 + rl) * Ec + k0 + chs, &lB[buf][r0 * 64]);
    }
  };
  stage(0, 0);
  __syncthreads();
  int buf = 0;
  for (int s = 0; s < Ec / 64; s++) {
    if (s + 1 < Ec / 64) stage((s + 1) * 64, buf ^ 1);
    gemm_mfma(lA[buf], lB[buf], acc, lane, wm, wn);
    __syncthreads();
    buf ^= 1;
  }
#pragma unroll
  for (int mf = 0; mf < 4; mf++) {
#pragma unroll
    for (int nf = 0; nf < 4; nf++) {
      int col = n0 + wn * 64 + nf * 16 + (lane & 15);
      float bs = bias[col];
#pragma unroll
      for (int r = 0; r < 4; r++) {
        int row = m0 + wm * 64 + mf * 16 + ((lane >> 4) << 2) + r;
        out[(size_t)row * Ec + col] = acc[mf][nf][r] + bs + res[(size_t)row * Ec + col];
      }
    }
  }
}

// ---------- flash attention: swapped QK^T, no max-tracking, l via ones-MFMA ----------
DEV void smstore(const f32x4 (&s)[4], short* lPbuf, int w, int lane,
                 bool diag, int qg, int koff) {
  const int gs = lane >> 4, l15 = lane & 15;
  const int m = w * 16 + l15;
#pragma unroll
  for (int mf = 0; mf < 4; mf++) {
    short4_t h;
#pragma unroll
    for (int r = 0; r < 4; r++) {
      float p = fexp2(s[mf][r]);
      if (diag && (koff + mf * 16 + gs * 4 + r) > qg) p = 0.f;
      h[r] = bfc(p);
    }
    int c = (2 * mf + (gs >> 1)) ^ (m & 7);
    *(short4_t*)&lPbuf[m * 64 + (c << 3) + (gs & 1) * 4] = h;
  }
}

__global__ __launch_bounds__(256) void k_attn4(const short* __restrict__ Qp,
                                               const short* __restrict__ Kp,
                                               const short* __restrict__ Vt,
                                               const int* __restrict__ maskp,
                                               short* __restrict__ ctx) {
  __shared__ short lK[2][4096];
  __shared__ short lV[2][4096];
  __shared__ short lP[2][4096];
  int lin = blockIdx.x + 16 * blockIdx.y;  // 512 blocks
  lin = (lin & 7) * 64 + (lin >> 3);       // XCD-contiguous (4 bh per XCD -> K/V L2 reuse)
  const int qi = lin & 15, bh = lin >> 4;
  const int t = threadIdx.x, lane = t & 63, w = t >> 6;
  const int gs = lane >> 4, l15 = lane & 15;
  const bool causal = maskp[0] != 0;
  const int b = bh >> 4, h = bh & 15;
  const size_t base = (size_t)bh * Sc * Dc;
  const int qtA = qi, qtB = NT - 1 - qi;
  const int ktmax = causal ? qtB : (NT - 1);

  bf16x8 aqA[2], aqB[2];
  {
    int qrA = qtA * 64 + w * 16 + l15;
    int qrB = qtB * 64 + w * 16 + l15;
#pragma unroll
    for (int kc = 0; kc < 2; kc++) {
      aqA[kc] = *(const bf16x8*)(Qp + base + (size_t)qrA * Dc + kc * 32 + (gs << 3));
      aqB[kc] = *(const bf16x8*)(Qp + base + (size_t)qrB * Dc + kc * 32 + (gs << 3));
    }
  }
  bf16x8 ones;
#pragma unroll
  for (int j = 0; j < 8; j++) ones[j] = (__bf16)1.0f;

  f32x4 oA[4], oB[4], lsA, lsB;
#pragma unroll
  for (int i = 0; i < 4; i++) {
    oA[i] = {0.f, 0.f, 0.f, 0.f};
    oB[i] = {0.f, 0.f, 0.f, 0.f};
  }
  lsA = {0.f, 0.f, 0.f, 0.f};
  lsB = {0.f, 0.f, 0.f, 0.f};

  const int rl = lane >> 3, chs = ((lane & 7) ^ rl) << 3;
  auto stage = [&](int kt_, int buf) {
    int koff = kt_ * 64;
#pragma unroll
    for (int j = 0; j < 2; j++) {
      int r0 = w * 16 + j * 8;
      gload16(Kp + base + (size_t)(koff + r0 + rl) * Dc + chs, &lK[buf][r0 * 64]);
      gload16(Vt + base + (size_t)(r0 + rl) * Sc + koff + chs, &lV[buf][r0 * 64]);
    }
  };
  stage(0, 0);
  __syncthreads();

  const int qgA = qtA * 64 + w * 16 + l15;
  const int qgB = qtB * 64 + w * 16 + l15;

  for (int kt = 0; kt <= ktmax; kt++) {
    const int cur = kt & 1, koff = kt * 64;
    if (kt < ktmax) stage(kt + 1, cur ^ 1);
    const bool actA = !causal || (kt <= qtA);

    // S^T = K Q^T (swapped): lane holds q=lane&15, k rows in regs
    f32x4 sA[4], sB[4];
#pragma unroll
    for (int mf = 0; mf < 4; mf++) {
      sA[mf] = {0.f, 0.f, 0.f, 0.f};
      sB[mf] = {0.f, 0.f, 0.f, 0.f};
    }
#pragma unroll
    for (int kc = 0; kc < 2; kc++) {
#pragma unroll
      for (int mf = 0; mf < 4; mf++) {
        int row = mf * 16 + l15;
        int ch = (kc * 4 + gs) ^ (row & 7);
        bf16x8 bk = *(const bf16x8*)&lK[cur][row * 64 + (ch << 3)];
        sB[mf] = __builtin_amdgcn_mfma_f32_16x16x32_bf16(bk, aqB[kc], sB[mf], 0, 0, 0);
        if (actA) sA[mf] = __builtin_amdgcn_mfma_f32_16x16x32_bf16(bk, aqA[kc], sA[mf], 0, 0, 0);
      }
    }
    smstore(sB, lP[0], w, lane, causal && (kt == qtB), qgB, koff);
    if (actA) smstore(sA, lP[1], w, lane, causal && (kt == qtA), qgA, koff);

    // O += P V ; l += P * ones  (row-sum on the matrix pipe, oacc layout)
#pragma unroll
    for (int kc = 0; kc < 2; kc++) {
      int prow = w * 16 + l15;
      int ch = (kc * 4 + gs) ^ (prow & 7);
      bf16x8 apB = *(const bf16x8*)&lP[0][prow * 64 + (ch << 3)];
      bf16x8 apA = {};
      if (actA) apA = *(const bf16x8*)&lP[1][prow * 64 + (ch << 3)];
#pragma unroll
      for (int df = 0; df < 4; df++) {
        int vr = df * 16 + l15;
        int ch2 = (kc * 4 + gs) ^ (vr & 7);
        bf16x8 bv = *(const bf16x8*)&lV[cur][vr * 64 + (ch2 << 3)];
        oB[df] = __builtin_amdgcn_mfma_f32_16x16x32_bf16(apB, bv, oB[df], 0, 0, 0);
        if (actA) oA[df] = __builtin_amdgcn_mfma_f32_16x16x32_bf16(apA, bv, oA[df], 0, 0, 0);
      }
      lsB = __builtin_amdgcn_mfma_f32_16x16x32_bf16(apB, ones, lsB, 0, 0, 0);
      if (actA) lsA = __builtin_amdgcn_mfma_f32_16x16x32_bf16(apA, ones, lsA, 0, 0, 0);
    }
    __syncthreads();
  }

#pragma unroll
  for (int r = 0; r < 4; r++) {
    float ib = 1.0f / lsB[r];
    float ia = 1.0f / lsA[r];
    int srB = qtB * 64 + w * 16 + (gs << 2) + r;
    int srA = qtA * 64 + w * 16 + (gs << 2) + r;
#pragma unroll
    for (int df = 0; df < 4; df++) {
      int col = h * 64 + df * 16 + l15;
      ctx[(size_t)(b * Sc + srB) * Ec + col] = f2bf(oB[df][r] * ib);
      ctx[(size_t)(b * Sc + srA) * Ec + col] = f2bf(oA[df][r] * ia);
    }
  }
}

// ---------- LayerNorm in-place on fp32 [M][E] ----------
__global__ __launch_bounds__(256) void k_ln(float* __restrict__ x,
                                            const float* __restrict__ gamma,
                                            const float* __restrict__ beta) {
  int row = blockIdx.x, t = threadIdx.x;
  float4 v = *(const float4*)(x + (size_t)row * Ec + t * 4);
  float s = v.x + v.y + v.z + v.w;
  float sq = v.x * v.x + v.y * v.y + v.z * v.z + v.w * v.w;
#pragma unroll
  for (int m = 1; m < 64; m <<= 1) {
    s += __shfl_xor(s, m);
    sq += __shfl_xor(sq, m);
  }
  __shared__ float red[8];
  if ((t & 63) == 0) {
    red[t >> 6] = s;
    red[4 + (t >> 6)] = sq;
  }
  __syncthreads();
  s = red[0] + red[1] + red[2] + red[3];
  sq = red[4] + red[5] + red[6] + red[7];
  float mu = s * (1.f / Ec);
  float var = sq * (1.f / Ec) - mu * mu;
  float rstd = rsqrtf(var + 1e-5f);
  float4 g = *(const float4*)(gamma + t * 4);
  float4 bb = *(const float4*)(beta + t * 4);
  v.x = (v.x - mu) * rstd * g.x + bb.x;
  v.y = (v.y - mu) * rstd * g.y + bb.y;
  v.z = (v.z - mu) * rstd * g.z + bb.z;
  v.w = (v.w - mu) * rstd * g.w + bb.w;
  *(float4*)(x + (size_t)row * Ec + t * 4) = v;
}

extern "C" void kernel_launch(void* const* d_in, const int* in_sizes, int n_in,
                              void* d_out, int out_size, void* d_ws, size_t ws_size,
                              hipStream_t stream) {
  const float* q = (const float*)d_in[0];
  const float* k = (const float*)d_in[1];
  const float* v = (const float*)d_in[2];
  const float* wq = (const float*)d_in[3];
  const float* bq = (const float*)d_in[4];
  const float* wk = (const float*)d_in[5];
  const float* bk = (const float*)d_in[6];
  const float* wv = (const float*)d_in[7];
  const float* bv = (const float*)d_in[8];
  const float* wo = (const float*)d_in[9];
  const float* bo = (const float*)d_in[10];
  const float* gamma = (const float*)d_in[11];
  const float* beta = (const float*)d_in[12];
  const int* maskp = (const int*)d_in[13];
  float* out = (float*)d_out;

  // workspace: 8MB weights + 24MB QKV + 8MB ctx = 40MB
  short* wtq = (short*)d_ws;
  short* wtk = wtq + (size_t)Ec * Ec;
  short* wtv = wtk + (size_t)Ec * Ec;
  short* wto = wtv + (size_t)Ec * Ec;
  short* Qp = wto + (size_t)Ec * Ec;   // [B,H,S,D] bf16 (pre-scaled by kQS)
  short* Kp = Qp + (size_t)Mc * Ec;    // [B,H,S,D] bf16
  short* Vt = Kp + (size_t)Mc * Ec;    // [B,H,D,S] bf16
  short* ctx = Vt + (size_t)Mc * Ec;   // [M][E] bf16

  // bf16 copies of q,k,v live in d_out (dead until k_gemm_o) + ctx slot
  short* xq = (short*)d_out;
  short* xk = xq + (size_t)Mc * Ec;
  short* xv = ctx;

  dim3 tb(256);

  Prep pargs;
  pargs.w[0] = wq; pargs.w[1] = wk; pargs.w[2] = wv; pargs.w[3] = wo;
  pargs.wt[0] = wtq; pargs.wt[1] = wtk; pargs.wt[2] = wtv; pargs.wt[3] = wto;
  pargs.x[0] = q; pargs.x[1] = k; pargs.x[2] = v;
  pargs.y[0] = xq; pargs.y[1] = xk; pargs.y[2] = xv;
  k_prep<<<dim3(4096 + 3 * (Mc * Ec / 2048)), tb, 0, stream>>>(pargs);

  QKV3 gargs;
  gargs.A[0] = xq; gargs.A[1] = xk; gargs.A[2] = xv;
  gargs.Bt[0] = wtq; gargs.Bt[1] = wtk; gargs.Bt[2] = wtv;
  gargs.bias[0] = bq; gargs.bias[1] = bk; gargs.bias[2] = bv;
  gargs.out[0] = Qp; gargs.out[1] = Kp; gargs.out[2] = Vt;
  k_gemm_qkv<<<dim3(Ec / 128, Mc / 128, 3), tb, 0, stream>>>(gargs);

  k_attn4<<<dim3(NT / 2, Bc * Hc), tb, 0, stream>>>(Qp, Kp, Vt, maskp, ctx);

  k_gemm_o<<<dim3(Ec / 128, Mc / 128), tb, 0, stream>>>(ctx, wto, bo, q, out);

  k_ln<<<dim3(Mc), tb, 0, stream>>>(out, gamma, beta);
}

// Round 6
// 146.863 us; speedup vs baseline: 2.1419x; 1.0863x over previous
//
#include <hip/hip_runtime.h>
#include <hip/hip_bf16.h>

typedef __bf16 bf16x8 __attribute__((ext_vector_type(8)));
typedef __attribute__((ext_vector_type(8))) short short8_t;
typedef __attribute__((ext_vector_type(4))) short short4_t;
typedef __attribute__((ext_vector_type(4))) float f32x4;

#define DEV __device__ __forceinline__

constexpr int Bc = 2, Sc = 2048, Ec = 1024, Hc = 16, Dc = 64;
constexpr int Mc = Bc * Sc;  // 4096
constexpr int NT = Sc / 64;  // 32 k-tiles
// fold 1/(sqrt(D)+1e-8) and log2(e) into Q projection
constexpr float kQS = (float)((1.0 / (8.0 + 1e-8)) * 1.4426950408889634);

DEV short f2bf(float f) {
  unsigned int u = __builtin_bit_cast(unsigned int, f);
  unsigned int r = u + 0x7fffu + ((u >> 16) & 1u);
  return (short)(r >> 16);
}
DEV short bfc(float f) { __bf16 h = (__bf16)f; return __builtin_bit_cast(short, h); }

DEV float fexp2(float x) {
#if __has_builtin(__builtin_amdgcn_exp2f)
  return __builtin_amdgcn_exp2f(x);
#else
  float r;
  asm("v_exp_f32 %0, %1" : "=v"(r) : "v"(x));
  return r;
#endif
}

DEV void gload16(const short* g, short* lds) {
  __builtin_amdgcn_global_load_lds((const __attribute__((address_space(1))) void*)g,
                                   (__attribute__((address_space(3))) void*)lds, 16, 0, 0);
}

// ---------- merged prep: 4x weight transpose->bf16 + 3x fp32->bf16 convert ----------
struct Prep {
  const float* w[4]; short* wt[4];
  const float* x[3]; short* y[3];
};
__global__ __launch_bounds__(256) void k_prep(Prep a) {
  const int bid = blockIdx.x;
  if (bid < 4096) {
    __shared__ float tile[32][33];
    const int z = bid >> 10, bk = (bid >> 5) & 31, bn = bid & 31;
    const float* w = a.w[z];
    short* wt = a.wt[z];
    int tx = threadIdx.x & 31, ty = threadIdx.x >> 5;
#pragma unroll
    for (int i = 0; i < 4; i++)
      tile[ty + i * 8][tx] = w[(size_t)(bk * 32 + ty + i * 8) * Ec + bn * 32 + tx];
    __syncthreads();
#pragma unroll
    for (int i = 0; i < 4; i++)
      wt[(size_t)(bn * 32 + ty + i * 8) * Ec + bk * 32 + tx] = f2bf(tile[tx][ty + i * 8]);
  } else {
    const int idx = bid - 4096;
    const int z = idx >> 11, c = idx & 2047;
    const float* x = a.x[z];
    short* y = a.y[z];
    size_t i = ((size_t)c * 256 + threadIdx.x) * 8;
    float4 v0 = *(const float4*)(x + i);
    float4 v1 = *(const float4*)(x + i + 4);
    short8_t h;
    h[0] = bfc(v0.x); h[1] = bfc(v0.y); h[2] = bfc(v0.z); h[3] = bfc(v0.w);
    h[4] = bfc(v1.x); h[5] = bfc(v1.y); h[6] = bfc(v1.z); h[7] = bfc(v1.w);
    *(short8_t*)(y + i) = h;
  }
}

// ---------- shared MFMA tile compute (128x128, BK=64) ----------
DEV void gemm_mfma(const short* lA, const short* lB, f32x4 (&acc)[4][4], int lane, int wm, int wn) {
#pragma unroll
  for (int kc = 0; kc < 2; kc++) {
    bf16x8 a[4], b[4];
#pragma unroll
    for (int mf = 0; mf < 4; mf++) {
      int row = wm * 64 + mf * 16 + (lane & 15);
      int ch = (kc * 4 + (lane >> 4)) ^ (row & 7);
      a[mf] = *(const bf16x8*)&lA[row * 64 + (ch << 3)];
    }
#pragma unroll
    for (int nf = 0; nf < 4; nf++) {
      int row = wn * 64 + nf * 16 + (lane & 15);
      int ch = (kc * 4 + (lane >> 4)) ^ (row & 7);
      b[nf] = *(const bf16x8*)&lB[row * 64 + (ch << 3)];
    }
#pragma unroll
    for (int mf = 0; mf < 4; mf++)
#pragma unroll
      for (int nf = 0; nf < 4; nf++)
        acc[mf][nf] = __builtin_amdgcn_mfma_f32_16x16x32_bf16(a[mf], b[nf], acc[mf][nf], 0, 0, 0);
  }
}

// ---------- QKV GEMM (z=3 merged, bf16 A, 2-phase dbuf) ----------
// z=0 -> Q [B,H,S,D] (scaled by kQS); z=1 -> K fragment-order (dense); z=2 -> V fragment-order (dense)
struct QKV3 { const short* A[3]; const short* Bt[3]; const float* bias[3]; short* out[3]; };

__global__ __launch_bounds__(256) void k_gemm_qkv(QKV3 args) {
  __shared__ short lA[2][128 * 64];
  __shared__ short lB[2][128 * 64];
  int lin = blockIdx.x + 8 * blockIdx.y + 256 * blockIdx.z;  // 768 blocks
  lin = (lin & 7) * 96 + (lin >> 3);                          // XCD-contiguous
  const int bx = lin & 7, by = (lin >> 3) & 31, z = lin >> 8;
  const short* A = args.A[z];
  const short* Bt = args.Bt[z];
  const float* bias = args.bias[z];
  short* out = args.out[z];
  const int t = threadIdx.x;
  const int m0 = by * 128, n0 = bx * 128;
  const int lane = t & 63, wid = t >> 6;
  const int wm = wid >> 1, wn = wid & 1;
  const int rl = lane >> 3, chs = ((lane & 7) ^ rl) << 3;

  f32x4 acc[4][4];
#pragma unroll
  for (int i = 0; i < 4; i++)
#pragma unroll
    for (int j = 0; j < 4; j++) acc[i][j] = {0.f, 0.f, 0.f, 0.f};

  auto stage = [&](int k0, int buf) {
#pragma unroll
    for (int j = 0; j < 4; j++) {
      int r0 = wid * 32 + j * 8;
      gload16(A + (size_t)(m0 + r0 + rl) * Ec + k0 + chs, &lA[buf][r0 * 64]);
      gload16(Bt + (size_t)(n0 + r0 + rl) * Ec + k0 + chs, &lB[buf][r0 * 64]);
    }
  };
  stage(0, 0);
  __syncthreads();
  int buf = 0;
  for (int s = 0; s < Ec / 64; s++) {
    if (s + 1 < Ec / 64) stage((s + 1) * 64, buf ^ 1);
    gemm_mfma(lA[buf], lB[buf], acc, lane, wm, wn);
    __syncthreads();
    buf ^= 1;
  }
#pragma unroll
  for (int mf = 0; mf < 4; mf++) {
#pragma unroll
    for (int nf = 0; nf < 4; nf++) {
      int col = n0 + wn * 64 + nf * 16 + (lane & 15);
      float bs = bias[col];
      int row0 = m0 + wm * 64 + mf * 16 + ((lane >> 4) << 2);
      int bh = ((row0 >> 11) << 4) + (col >> 6);
      int d = col & 63;
      size_t bhbase = (size_t)bh * Sc * Dc;
      if (z == 0) {  // Q: [B,H,S,D]
#pragma unroll
        for (int r = 0; r < 4; r++) {
          int row = row0 + r;
          size_t off = bhbase + (size_t)(row & 2047) * Dc + d;
          out[off] = f2bf((acc[mf][nf][r] + bs) * kQS);
        }
      } else if (z == 1) {  // K fragment order (dense): [s>>4](1024) [d>>5](512) [gs=(d>>3)&3](128) [s&15](8) [d&7]
#pragma unroll
        for (int r = 0; r < 4; r++) {
          int s = (row0 + r) & 2047;
          size_t off = bhbase + (size_t)(s >> 4) * 1024 + ((d >> 5) * 512) +
                       (((d >> 3) & 3) * 128) + ((s & 15) * 8) + (d & 7);
          out[off] = f2bf(acc[mf][nf][r] + bs);
        }
      } else {  // V fragment order (dense): [s>>6](4096) [kc=(s>>5)&1](2048) [df=(d>>4)&3](512) [gs=(s>>3)&3](128) [d&15](8) [s&7]
        short4_t h;
#pragma unroll
        for (int r = 0; r < 4; r++) h[r] = f2bf(acc[mf][nf][r] + bs);
        int s0 = row0 & 2047;
        size_t off = bhbase + (size_t)(s0 >> 6) * 4096 + (((s0 >> 5) & 1) * 2048) +
                     (((d >> 4) & 3) * 512) + ((((s0 >> 3) & 3) * 16 + (d & 15)) * 8) + (s0 & 7);
        *(short4_t*)&out[off] = h;
      }
    }
  }
}

// ---------- out-proj GEMM (2-phase dbuf): fp32 out = ctx*Wo^T + bias + residual ----------
__global__ __launch_bounds__(256) void k_gemm_o(const short* __restrict__ A,
                                                const short* __restrict__ Bt,
                                                const float* __restrict__ bias,
                                                const float* __restrict__ res,
                                                float* __restrict__ out) {
  __shared__ short lA[2][128 * 64];
  __shared__ short lB[2][128 * 64];
  int lin = blockIdx.x + 8 * blockIdx.y;  // 256 blocks
  lin = (lin & 7) * 32 + (lin >> 3);
  const int bx = lin & 7, by = lin >> 3;
  const int t = threadIdx.x;
  const int m0 = by * 128, n0 = bx * 128;
  const int lane = t & 63, wid = t >> 6;
  const int wm = wid >> 1, wn = wid & 1;
  const int rl = lane >> 3, chs = ((lane & 7) ^ rl) << 3;

  f32x4 acc[4][4];
#pragma unroll
  for (int i = 0; i < 4; i++)
#pragma unroll
    for (int j = 0; j < 4; j++) acc[i][j] = {0.f, 0.f, 0.f, 0.f};

  auto stage = [&](int k0, int buf) {
#pragma unroll
    for (int j = 0; j < 4; j++) {
      int r0 = wid * 32 + j * 8;
      gload16(A + (size_t)(m0 + r0 + rl) * Ec + k0 + chs, &lA[buf][r0 * 64]);
      gload16(Bt + (size_t)(n0 + r0 + rl) * Ec + k0 + chs, &lB[buf][r0 * 64]);
    }
  };
  stage(0, 0);
  __syncthreads();
  int buf = 0;
  for (int s = 0; s < Ec / 64; s++) {
    if (s + 1 < Ec / 64) stage((s + 1) * 64, buf ^ 1);
    gemm_mfma(lA[buf], lB[buf], acc, lane, wm, wn);
    __syncthreads();
    buf ^= 1;
  }
#pragma unroll
  for (int mf = 0; mf < 4; mf++) {
#pragma unroll
    for (int nf = 0; nf < 4; nf++) {
      int col = n0 + wn * 64 + nf * 16 + (lane & 15);
      float bs = bias[col];
#pragma unroll
      for (int r = 0; r < 4; r++) {
        int row = m0 + wm * 64 + mf * 16 + ((lane >> 4) << 2) + r;
        out[(size_t)row * Ec + col] = acc[mf][nf][r] + bs + res[(size_t)row * Ec + col];
      }
    }
  }
}

// ---------- flash attention: fragment-direct K/V, barrier-light, wave-local P ----------
__global__ __launch_bounds__(256, 4) void k_attn5(const short* __restrict__ Qp,
                                                  const short* __restrict__ Kf,
                                                  const short* __restrict__ Vf,
                                                  const int* __restrict__ maskp,
                                                  short* __restrict__ ctx) {
  __shared__ short lP[64 * 64];  // per-wave rows [w*16, w*16+16)
  const int lin = blockIdx.x;    // lin = qtord*32 + bh ; lin%8 == bh%8 (XCD locality)
  const int bh = lin & 31, qt = (NT - 1) - (lin >> 5);  // long blocks (qt high) first
  const int t = threadIdx.x, lane = t & 63, w = t >> 6;
  const int gs = lane >> 4, l15 = lane & 15;
  const bool causal = maskp[0] != 0;
  const int b = bh >> 4, h = bh & 15;
  const size_t base = (size_t)bh * Sc * Dc;
  const int ktend = causal ? qt : (NT - 1);

  // Q fragments (16 q-rows per wave)
  bf16x8 aq[2];
  {
    const short* qptr = Qp + base + (size_t)(qt * 64 + w * 16 + l15) * Dc + gs * 8;
    aq[0] = *(const bf16x8*)(qptr);
    aq[1] = *(const bf16x8*)(qptr + 32);
  }
  bf16x8 ones;
#pragma unroll
  for (int j = 0; j < 8; j++) ones[j] = (__bf16)1.0f;

  f32x4 oacc[4], lsum;
#pragma unroll
  for (int i = 0; i < 4; i++) oacc[i] = {0.f, 0.f, 0.f, 0.f};
  lsum = {0.f, 0.f, 0.f, 0.f};

  // P LDS addresses (constant per lane, wave-private rows)
  const int prow = w * 16 + l15, pswz = l15 & 7;
  short* pw[4];
  const short* pr[2];
#pragma unroll
  for (int mf = 0; mf < 4; mf++)
    pw[mf] = &lP[prow * 64 + (((2 * mf + (gs >> 1)) ^ pswz) << 3) + (gs & 1) * 4];
#pragma unroll
  for (int kc = 0; kc < 2; kc++)
    pr[kc] = &lP[prow * 64 + (((kc * 4 + gs) ^ pswz) << 3)];

  const short* Kb = Kf + base + lane * 8;
  const short* Vb = Vf + base + lane * 8;

  for (int kt = 0; kt <= ktend; kt++) {
    // K fragments: 8 coalesced dwordx4 loads (dense: kt*4096, mf*1024, kc*512)
    const short* kp = Kb + kt * 4096;
    bf16x8 kf[2][4];
#pragma unroll
    for (int mf = 0; mf < 4; mf++) {
      kf[0][mf] = *(const bf16x8*)(kp + mf * 1024);
      kf[1][mf] = *(const bf16x8*)(kp + mf * 1024 + 512);
    }
    // S^T = K Q^T
    f32x4 s[4];
#pragma unroll
    for (int mf = 0; mf < 4; mf++) s[mf] = {0.f, 0.f, 0.f, 0.f};
#pragma unroll
    for (int kc = 0; kc < 2; kc++)
#pragma unroll
      for (int mf = 0; mf < 4; mf++)
        s[mf] = __builtin_amdgcn_mfma_f32_16x16x32_bf16(kf[kc][mf], aq[kc], s[mf], 0, 0, 0);

    // exp2 -> bf16 P (mask only on the diagonal tile)
    if (causal && kt == qt) {
      const int qloc = w * 16 + l15;
#pragma unroll
      for (int mf = 0; mf < 4; mf++) {
        short4_t hh;
#pragma unroll
        for (int r = 0; r < 4; r++) {
          float p = fexp2(s[mf][r]);
          if ((mf * 16 + gs * 4 + r) > qloc) p = 0.f;
          hh[r] = bfc(p);
        }
        *(short4_t*)pw[mf] = hh;
      }
    } else {
#pragma unroll
      for (int mf = 0; mf < 4; mf++) {
        short4_t hh;
#pragma unroll
        for (int r = 0; r < 4; r++) hh[r] = bfc(fexp2(s[mf][r]));
        *(short4_t*)pw[mf] = hh;
      }
    }

    // V fragments + P fragments (dense: kt*4096, kc*2048, df*512)
    const short* vp = Vb + kt * 4096;
    bf16x8 pa[2];
    pa[0] = *(const bf16x8*)pr[0];
    pa[1] = *(const bf16x8*)pr[1];
#pragma unroll
    for (int kc = 0; kc < 2; kc++) {
      bf16x8 vf[4];
#pragma unroll
      for (int df = 0; df < 4; df++)
        vf[df] = *(const bf16x8*)(vp + kc * 2048 + df * 512);
      lsum = __builtin_amdgcn_mfma_f32_16x16x32_bf16(pa[kc], ones, lsum, 0, 0, 0);
#pragma unroll
      for (int df = 0; df < 4; df++)
        oacc[df] = __builtin_amdgcn_mfma_f32_16x16x32_bf16(pa[kc], vf[df], oacc[df], 0, 0, 0);
    }
    __syncthreads();  // keep the block's 4 waves on the same K/V tile (L1 reuse)
  }

#pragma unroll
  for (int r = 0; r < 4; r++) {
    float ib = 1.0f / lsum[r];
    int sr = qt * 64 + w * 16 + (gs << 2) + r;
#pragma unroll
    for (int df = 0; df < 4; df++) {
      int col = h * 64 + df * 16 + l15;
      ctx[(size_t)(b * Sc + sr) * Ec + col] = f2bf(oacc[df][r] * ib);
    }
  }
}

// ---------- LayerNorm in-place on fp32 [M][E] ----------
__global__ __launch_bounds__(256) void k_ln(float* __restrict__ x,
                                            const float* __restrict__ gamma,
                                            const float* __restrict__ beta) {
  int row = blockIdx.x, t = threadIdx.x;
  float4 v = *(const float4*)(x + (size_t)row * Ec + t * 4);
  float s = v.x + v.y + v.z + v.w;
  float sq = v.x * v.x + v.y * v.y + v.z * v.z + v.w * v.w;
#pragma unroll
  for (int m = 1; m < 64; m <<= 1) {
    s += __shfl_xor(s, m);
    sq += __shfl_xor(sq, m);
  }
  __shared__ float red[8];
  if ((t & 63) == 0) {
    red[t >> 6] = s;
    red[4 + (t >> 6)] = sq;
  }
  __syncthreads();
  s = red[0] + red[1] + red[2] + red[3];
  sq = red[4] + red[5] + red[6] + red[7];
  float mu = s * (1.f / Ec);
  float var = sq * (1.f / Ec) - mu * mu;
  float rstd = rsqrtf(var + 1e-5f);
  float4 g = *(const float4*)(gamma + t * 4);
  float4 bb = *(const float4*)(beta + t * 4);
  v.x = (v.x - mu) * rstd * g.x + bb.x;
  v.y = (v.y - mu) * rstd * g.y + bb.y;
  v.z = (v.z - mu) * rstd * g.z + bb.z;
  v.w = (v.w - mu) * rstd * g.w + bb.w;
  *(float4*)(x + (size_t)row * Ec + t * 4) = v;
}

extern "C" void kernel_launch(void* const* d_in, const int* in_sizes, int n_in,
                              void* d_out, int out_size, void* d_ws, size_t ws_size,
                              hipStream_t stream) {
  const float* q = (const float*)d_in[0];
  const float* k = (const float*)d_in[1];
  const float* v = (const float*)d_in[2];
  const float* wq = (const float*)d_in[3];
  const float* bq = (const float*)d_in[4];
  const float* wk = (const float*)d_in[5];
  const float* bk = (const float*)d_in[6];
  const float* wv = (const float*)d_in[7];
  const float* bv = (const float*)d_in[8];
  const float* wo = (const float*)d_in[9];
  const float* bo = (const float*)d_in[10];
  const float* gamma = (const float*)d_in[11];
  const float* beta = (const float*)d_in[12];
  const int* maskp = (const int*)d_in[13];
  float* out = (float*)d_out;

  short* wtq = (short*)d_ws;
  short* wtk = wtq + (size_t)Ec * Ec;
  short* wtv = wtk + (size_t)Ec * Ec;
  short* wto = wtv + (size_t)Ec * Ec;
  short* Qp = wto + (size_t)Ec * Ec;   // [B,H,S,D] bf16 (pre-scaled by kQS)
  short* Kf = Qp + (size_t)Mc * Ec;    // fragment-order K (dense)
  short* Vf = Kf + (size_t)Mc * Ec;    // fragment-order V (dense)
  short* ctx = Vf + (size_t)Mc * Ec;   // [M][E] bf16

  short* xq = (short*)d_out;
  short* xk = xq + (size_t)Mc * Ec;
  short* xv = ctx;

  dim3 tb(256);

  Prep pargs;
  pargs.w[0] = wq; pargs.w[1] = wk; pargs.w[2] = wv; pargs.w[3] = wo;
  pargs.wt[0] = wtq; pargs.wt[1] = wtk; pargs.wt[2] = wtv; pargs.wt[3] = wto;
  pargs.x[0] = q; pargs.x[1] = k; pargs.x[2] = v;
  pargs.y[0] = xq; pargs.y[1] = xk; pargs.y[2] = xv;
  k_prep<<<dim3(4096 + 3 * (Mc * Ec / 2048)), tb, 0, stream>>>(pargs);

  QKV3 gargs;
  gargs.A[0] = xq; gargs.A[1] = xk; gargs.A[2] = xv;
  gargs.Bt[0] = wtq; gargs.Bt[1] = wtk; gargs.Bt[2] = wtv;
  gargs.bias[0] = bq; gargs.bias[1] = bk; gargs.bias[2] = bv;
  gargs.out[0] = Qp; gargs.out[1] = Kf; gargs.out[2] = Vf;
  k_gemm_qkv<<<dim3(Ec / 128, Mc / 128, 3), tb, 0, stream>>>(gargs);

  k_attn5<<<dim3(NT * Bc * Hc), tb, 0, stream>>>(Qp, Kf, Vf, maskp, ctx);

  k_gemm_o<<<dim3(Ec / 128, Mc / 128), tb, 0, stream>>>(ctx, wto, bo, q, out);

  k_ln<<<dim3(Mc), tb, 0, stream>>>(out, gamma, beta);
}